// Round 4
// baseline (102.299 us; speedup 1.0000x reference)
//
#include <hip/hip_runtime.h>
#include <float.h>

// E=4, L=8, S=512, F=32, G=512.

#if __has_builtin(__builtin_amdgcn_exp2f)
__device__ __forceinline__ float fast_exp2(float x) { return __builtin_amdgcn_exp2f(x); }
#else
__device__ __forceinline__ float fast_exp2(float x) { return exp2f(x); }
#endif

// ---- workspace layout (float offsets) ----
#define PT_OFF    0        // proj^T [E][L][F][S] = 524288 floats (unscaled)
#define SX_OFF    524288   // [256 blk][32 f] sum(x)
#define SXX_OFF   532480   // [256 blk][32 f] sum(x^2)
#define MIN_OFF   540672   // [256] per-block min
#define MAX_OFF   540928   // [256] per-block max
#define CNT_OFF   541184   // completion counter (int)

// ---------- K1: proj^T + std partials + min/max (known-good from R2) ----------
__global__ __launch_bounds__(256) void stage_prep(const float* __restrict__ matrix,
                                                  const float* __restrict__ params,
                                                  float* __restrict__ PT,
                                                  float* __restrict__ sxg,
                                                  float* __restrict__ sxxg,
                                                  float* __restrict__ minp,
                                                  float* __restrict__ maxp,
                                                  int* __restrict__ counter) {
    __shared__ float M[64][33];    // +1 pad: proj pass reads column-wise
    __shared__ float Pm[32][32];
    __shared__ float sxr[8][32], sxxr[8][32];
    __shared__ float rmin[4], rmax[4];
    const int bid = blockIdx.x;        // (e*8+l)*8 + stile
    const int s0 = (bid & 7) << 6;
    const int el = bid >> 3;
    const int t = threadIdx.x;
    if (bid == 0 && t == 0) *counter = 0;   // reset for K2's last-block trick
    for (int k = t; k < 1024; k += 256) Pm[k >> 5][k & 31] = params[k];
    const float* mb = matrix + (size_t)(el * 512 + s0) * 32;
    for (int k = t; k < 2048; k += 256) M[k >> 5][k & 31] = mb[k];
    __syncthreads();
    {
        const int f = t & 31, r = t >> 5;
        float sx = 0.f, sxx = 0.f;
        #pragma unroll
        for (int k = 0; k < 8; ++k) {
            float v = M[r * 8 + k][f];
            sx += v; sxx += v * v;
        }
        sxr[r][f] = sx; sxxr[r][f] = sxx;
    }
    const int s = t & 63;
    const int g0 = t >> 6;
    float lmin = FLT_MAX, lmax = -FLT_MAX;
    #pragma unroll
    for (int pass = 0; pass < 8; ++pass) {
        const int g = (pass << 2) + g0;
        float acc = 0.f;
        #pragma unroll
        for (int fp = 0; fp < 32; ++fp) acc += M[s][fp] * Pm[fp][g];
        lmin = fminf(lmin, acc);
        lmax = fmaxf(lmax, acc);
        PT[(size_t)(el * 32 + g) * 512 + s0 + s] = acc;
    }
    #pragma unroll
    for (int off = 32; off >= 1; off >>= 1) {
        lmin = fminf(lmin, __shfl_xor(lmin, off, 64));
        lmax = fmaxf(lmax, __shfl_xor(lmax, off, 64));
    }
    if ((t & 63) == 0) { rmin[t >> 6] = lmin; rmax[t >> 6] = lmax; }
    __syncthreads();
    if (t < 32) {
        float a = 0.f, b = 0.f;
        #pragma unroll
        for (int r = 0; r < 8; ++r) { a += sxr[r][t]; b += sxxr[r][t]; }
        sxg[bid * 32 + t] = a;
        sxxg[bid * 32 + t] = b;
    }
    if (t == 0) {
        minp[bid] = fminf(fminf(rmin[0], rmin[1]), fminf(rmin[2], rmin[3]));
        maxp[bid] = fmaxf(fmaxf(rmax[0], rmax[1]), fmaxf(rmax[2], rmax[3]));
    }
}

// ---------- K2: consts (redundant) + KDE + pair L1 + outputs ----------
// 256 blocks = one per (l,f), 1024 threads = (e = t>>8, gl = t&255), 2 grid
// points per thread (gl, gl+256). Last finished block computes the scalars.
__global__ __launch_bounds__(1024, 4) void stage_kde2(const float* __restrict__ PT,
                                                      const float* __restrict__ sxg,
                                                      const float* __restrict__ sxxg,
                                                      const float* __restrict__ minp,
                                                      const float* __restrict__ maxp,
                                                      const int* __restrict__ dlen,
                                                      int* __restrict__ counter,
                                                      float* __restrict__ out) {
    __shared__ __align__(16) float xs[4][512];
    __shared__ float red[4][512];
    __shared__ float wsum[16], wmn[16], wmx[16];
    __shared__ float wred[8][6];
    __shared__ float csh[6];
    __shared__ int lastf;
    const int t = threadIdx.x;
    const int lf = blockIdx.x;
    const int l = lf >> 5, f = lf & 31;

    // ---- consts: every block redundantly reduces K1's tiny partials ----
    {
        const int el = t >> 5, fc = t & 31;          // 1024 (el,f) pairs
        const int base = el * 256 + fc;
        float Sx = 0.f, Sxx = 0.f;
        #pragma unroll
        for (int tile = 0; tile < 8; ++tile) { Sx += sxg[base + tile * 32]; Sxx += sxxg[base + tile * 32]; }
        const float mean = Sx * (1.0f / 512.0f);
        const float var = (Sxx - Sx * mean) * (1.0f / 511.0f);   // ddof=1
        float sf = sqrtf(fmaxf(var, 0.f));
        float mn = (t < 256) ? minp[t] : FLT_MAX;
        float mx = (t < 256) ? maxp[t] : -FLT_MAX;
        #pragma unroll
        for (int off = 32; off >= 1; off >>= 1) {
            sf += __shfl_xor(sf, off, 64);
            mn = fminf(mn, __shfl_xor(mn, off, 64));
            mx = fmaxf(mx, __shfl_xor(mx, off, 64));
        }
        if ((t & 63) == 0) { wsum[t >> 6] = sf; wmn[t >> 6] = mn; wmx[t >> 6] = mx; }
        __syncthreads();
        if (t == 0) {
            float s = 0.f, lo = FLT_MAX, hi = -FLT_MAX;
            #pragma unroll
            for (int w = 0; w < 16; ++w) {
                s += wsum[w]; lo = fminf(lo, wmn[w]); hi = fmaxf(hi, wmx[w]);
            }
            const float stdv = s * (1.0f / 1024.0f);
            const float left  = lo / stdv;
            const float right = hi / stdv;
            const float bw = 1.06f * 0.28717458874925877f;     // mean(std(m)) == 1
            const float delta = (right - left) * (1.0f / 512.0f);
            const float gstep = (right - left) * (1.0f / 511.0f);
            const float divisor = 2.5066282746310002f * bw;
            const float cpos = (0.5f / (bw * bw)) * 1.4426950408889634f;
            const float kf = sqrtf(cpos);          // arg = -(k*x - k*p)^2
            csh[0] = left;
            csh[1] = gstep;
            csh[2] = kf;
            csh[3] = (1.0f / stdv) * kf;           // xscale
            csh[4] = delta * 0.5f / divisor;       // final scale
        }
    }
    __syncthreads();
    const float left = csh[0], gstep = csh[1], kf = csh[2], xscale = csh[3];

    // ---- stage samples ----
    #pragma unroll
    for (int k = t; k < 2048; k += 1024) {
        const int e2 = k >> 9, s2 = k & 511;
        xs[e2][s2] = PT[((size_t)(((e2 << 3) + l) * 32 + f) << 9) + s2] * xscale;
    }
    __syncthreads();

    // ---- KDE ----
    const int e = t >> 8, gl = t & 255;
    const int len = dlen[(e << 3) + l];            // wave-uniform
    const float pa = fmaf((float)gl, gstep, left) * kf;
    const float pb = fmaf((float)(gl + 256), gstep, left) * kf;
    const float* __restrict__ x = xs[e];
    float2 A0 = {0.f, 0.f}, A1 = {0.f, 0.f}, A2 = {0.f, 0.f}, A3 = {0.f, 0.f};
    int s = 0;
    for (; s + 4 <= len; s += 4) {
        const float4 v = *reinterpret_cast<const float4*>(&x[s]);
        const float d0a = v.x - pa, d0b = v.x - pb;
        const float d1a = v.y - pa, d1b = v.y - pb;
        const float d2a = v.z - pa, d2b = v.z - pb;
        const float d3a = v.w - pa, d3b = v.w - pb;
        A0.x += fast_exp2(-(d0a * d0a)); A0.y += fast_exp2(-(d0b * d0b));
        A1.x += fast_exp2(-(d1a * d1a)); A1.y += fast_exp2(-(d1b * d1b));
        A2.x += fast_exp2(-(d2a * d2a)); A2.y += fast_exp2(-(d2b * d2b));
        A3.x += fast_exp2(-(d3a * d3a)); A3.y += fast_exp2(-(d3b * d3b));
    }
    for (; s < len; ++s) {
        const float da = x[s] - pa, db = x[s] - pb;
        A0.x += fast_exp2(-(da * da)); A0.y += fast_exp2(-(db * db));
    }
    const float inv_len = 1.0f / (float)len;
    red[e][gl]       = ((A0.x + A1.x) + (A2.x + A3.x)) * inv_len;
    red[e][gl + 256] = ((A0.y + A1.y) + (A2.y + A3.y)) * inv_len;
    __syncthreads();

    // ---- pairwise |diff| summed over g, all in-block ----
    if (t < 512) {
        const float r0 = red[0][t], r1 = red[1][t], r2 = red[2][t], r3 = red[3][t];
        float pr[6];
        pr[0] = fabsf(r0 - r1);
        pr[1] = fabsf(r0 - r2);
        pr[2] = fabsf(r0 - r3);
        pr[3] = fabsf(r1 - r2);
        pr[4] = fabsf(r1 - r3);
        pr[5] = fabsf(r2 - r3);
        #pragma unroll
        for (int pi = 0; pi < 6; ++pi) {
            float v = pr[pi];
            #pragma unroll
            for (int off = 32; off >= 1; off >>= 1) v += __shfl_xor(v, off, 64);
            if ((t & 63) == 0) wred[t >> 6][pi] = v;
        }
    }
    __syncthreads();
    if (t == 0) {
        const float scale = csh[4];
        float v[6];
        #pragma unroll
        for (int pi = 0; pi < 6; ++pi) {
            float sm = 0.f;
            #pragma unroll
            for (int w = 0; w < 8; ++w) sm += wred[w][pi];
            v[pi] = sm * scale;
        }
        float testv = v[0];
        #pragma unroll
        for (int pi = 1; pi < 6; ++pi) testv = fmaxf(testv, v[pi]);
        const float trainv = fmaxf(fmaxf(v[0], v[1]), v[3]);  // pairs (0,1),(0,2),(1,2)
        out[lf] = trainv;
        out[256 + lf] = testv;
        __threadfence();   // make out[] visible device-wide before the atomic
        const int old = __hip_atomic_fetch_add(counter, 1, __ATOMIC_ACQ_REL,
                                               __HIP_MEMORY_SCOPE_AGENT);
        lastf = (old == 255);
    }
    __syncthreads();

    // ---- last finished block computes the two scalar outputs ----
    if (lastf && t < 64) {
        const int ff = t & 31;
        const int base = (t >= 32) ? 256 : 0;      // lanes 0-31: train, 32-63: test
        float m = -FLT_MAX;
        #pragma unroll
        for (int ll = 0; ll < 8; ++ll) {
            const float val = __hip_atomic_load(&out[base + ll * 32 + ff],
                                                __ATOMIC_RELAXED, __HIP_MEMORY_SCOPE_AGENT);
            m = fmaxf(m, val);
        }
        #pragma unroll
        for (int off = 16; off >= 1; off >>= 1) m += __shfl_xor(m, off, 32);
        if (ff == 0) out[512 + (base ? 1 : 0)] = m * (1.0f / 32.0f);
    }
}

extern "C" void kernel_launch(void* const* d_in, const int* in_sizes, int n_in,
                              void* d_out, int out_size, void* d_ws, size_t ws_size,
                              hipStream_t stream) {
    (void)in_sizes; (void)n_in; (void)out_size; (void)ws_size;
    const float* matrix = (const float*)d_in[0];
    const float* params = (const float*)d_in[1];
    const int*   dlen   = (const int*)d_in[2];
    float* out = (float*)d_out;
    float* ws  = (float*)d_ws;
    float* PT   = ws + PT_OFF;
    float* sxg  = ws + SX_OFF;
    float* sxxg = ws + SXX_OFF;
    float* minp = ws + MIN_OFF;
    float* maxp = ws + MAX_OFF;
    int*   cnt  = (int*)(ws + CNT_OFF);

    hipLaunchKernelGGL(stage_prep, dim3(256), dim3(256), 0, stream,
                       matrix, params, PT, sxg, sxxg, minp, maxp, cnt);
    hipLaunchKernelGGL(stage_kde2, dim3(256), dim3(1024), 0, stream,
                       PT, sxg, sxxg, minp, maxp, dlen, cnt, out);
}

// Round 5
// 102.139 us; speedup vs baseline: 1.0016x; 1.0016x over previous
//
#include <hip/hip_runtime.h>
#include <float.h>

// E=4, L=8, S=512, F=32, G=512.

#if __has_builtin(__builtin_amdgcn_exp2f)
__device__ __forceinline__ float fast_exp2(float x) { return __builtin_amdgcn_exp2f(x); }
#else
__device__ __forceinline__ float fast_exp2(float x) { return exp2f(x); }
#endif

// ---- workspace layout (float offsets) ----
#define PT_OFF    0        // proj^T [E][L][F][S] = 524288 floats (unscaled)
#define SX_OFF    524288   // [256 blk][32 f] sum(x)
#define SXX_OFF   532480   // [256 blk][32 f] sum(x^2)
#define MIN_OFF   540672   // [256] per-block min
#define MAX_OFF   540928   // [256] per-block max
#define CNT_OFF   541184   // completion counter (int)

// ---------- K1: proj^T + std partials + min/max ----------
__global__ __launch_bounds__(256) void stage_prep(const float* __restrict__ matrix,
                                                  const float* __restrict__ params,
                                                  float* __restrict__ PT,
                                                  float* __restrict__ sxg,
                                                  float* __restrict__ sxxg,
                                                  float* __restrict__ minp,
                                                  float* __restrict__ maxp,
                                                  int* __restrict__ counter) {
    __shared__ float M[64][33];    // +1 pad: proj pass reads column-wise
    __shared__ float Pm[32][32];
    __shared__ float sxr[8][32], sxxr[8][32];
    __shared__ float rmin[4], rmax[4];
    const int bid = blockIdx.x;        // (e*8+l)*8 + stile
    const int s0 = (bid & 7) << 6;
    const int el = bid >> 3;
    const int t = threadIdx.x;
    if (bid == 0 && t == 0) *counter = 0;   // reset for K2's last-block trick
    // params: 1024 floats = 256 float4, one per thread
    {
        const float4 v = reinterpret_cast<const float4*>(params)[t];
        const int base = t << 2;
        Pm[base >> 5][base & 31]       = v.x;
        Pm[base >> 5][(base & 31) + 1] = v.y;
        Pm[base >> 5][(base & 31) + 2] = v.z;
        Pm[base >> 5][(base & 31) + 3] = v.w;
    }
    // matrix tile: 2048 floats = 512 float4, two per thread
    const float4* mb4 = reinterpret_cast<const float4*>(matrix + (size_t)(el * 512 + s0) * 32);
    #pragma unroll
    for (int k = t; k < 512; k += 256) {
        const float4 v = mb4[k];
        const int base = k << 2;
        M[base >> 5][base & 31]       = v.x;
        M[base >> 5][(base & 31) + 1] = v.y;
        M[base >> 5][(base & 31) + 2] = v.z;
        M[base >> 5][(base & 31) + 3] = v.w;
    }
    __syncthreads();
    {
        const int f = t & 31, r = t >> 5;
        float sx = 0.f, sxx = 0.f;
        #pragma unroll
        for (int k = 0; k < 8; ++k) {
            float v = M[r * 8 + k][f];
            sx += v; sxx += v * v;
        }
        sxr[r][f] = sx; sxxr[r][f] = sxx;
    }
    const int s = t & 63;
    const int g0 = t >> 6;
    float lmin = FLT_MAX, lmax = -FLT_MAX;
    #pragma unroll
    for (int pass = 0; pass < 8; ++pass) {
        const int g = (pass << 2) + g0;
        float acc = 0.f;
        #pragma unroll
        for (int fp = 0; fp < 32; ++fp) acc += M[s][fp] * Pm[fp][g];
        lmin = fminf(lmin, acc);
        lmax = fmaxf(lmax, acc);
        PT[(size_t)(el * 32 + g) * 512 + s0 + s] = acc;
    }
    #pragma unroll
    for (int off = 32; off >= 1; off >>= 1) {
        lmin = fminf(lmin, __shfl_xor(lmin, off, 64));
        lmax = fmaxf(lmax, __shfl_xor(lmax, off, 64));
    }
    if ((t & 63) == 0) { rmin[t >> 6] = lmin; rmax[t >> 6] = lmax; }
    __syncthreads();
    if (t < 32) {
        float a = 0.f, b = 0.f;
        #pragma unroll
        for (int r = 0; r < 8; ++r) { a += sxr[r][t]; b += sxxr[r][t]; }
        sxg[bid * 32 + t] = a;
        sxxg[bid * 32 + t] = b;
    }
    if (t == 0) {
        minp[bid] = fminf(fminf(rmin[0], rmin[1]), fminf(rmin[2], rmin[3]));
        maxp[bid] = fmaxf(fmaxf(rmax[0], rmax[1]), fmaxf(rmax[2], rmax[3]));
    }
}

// ---------- K2: consts (redundant) + KDE + pair L1 + outputs ----------
// 256 blocks = one per (l,f); 1024 threads = (h = t>>9, g = t&511).
// Thread sums envs {2h, 2h+1} at its single grid point g — per-thread work
// = len(2h)+len(2h+1), balancing waves (vs max over single envs).
__global__ __launch_bounds__(1024, 4) void stage_kde2(const float* __restrict__ PT,
                                                      const float* __restrict__ sxg,
                                                      const float* __restrict__ sxxg,
                                                      const float* __restrict__ minp,
                                                      const float* __restrict__ maxp,
                                                      const int* __restrict__ dlen,
                                                      int* __restrict__ counter,
                                                      float* __restrict__ out) {
    __shared__ __align__(16) float xs[4][512];
    __shared__ float red[4][512];
    __shared__ float wsum[16], wmn[16], wmx[16];
    __shared__ float wred[8][6];
    __shared__ float csh[6];
    __shared__ int lastf;
    const int t = threadIdx.x;
    const int lf = blockIdx.x;
    const int l = lf >> 5, f = lf & 31;

    // ---- consts: every block redundantly reduces K1's tiny partials ----
    {
        const int el = t >> 5, fc = t & 31;          // 1024 (el,f) pairs
        const int base = el * 256 + fc;
        float Sx = 0.f, Sxx = 0.f;
        #pragma unroll
        for (int tile = 0; tile < 8; ++tile) { Sx += sxg[base + tile * 32]; Sxx += sxxg[base + tile * 32]; }
        const float mean = Sx * (1.0f / 512.0f);
        const float var = (Sxx - Sx * mean) * (1.0f / 511.0f);   // ddof=1
        float sf = sqrtf(fmaxf(var, 0.f));
        float mn = (t < 256) ? minp[t] : FLT_MAX;
        float mx = (t < 256) ? maxp[t] : -FLT_MAX;
        #pragma unroll
        for (int off = 32; off >= 1; off >>= 1) {
            sf += __shfl_xor(sf, off, 64);
            mn = fminf(mn, __shfl_xor(mn, off, 64));
            mx = fmaxf(mx, __shfl_xor(mx, off, 64));
        }
        if ((t & 63) == 0) { wsum[t >> 6] = sf; wmn[t >> 6] = mn; wmx[t >> 6] = mx; }
        __syncthreads();
        if (t == 0) {
            float s = 0.f, lo = FLT_MAX, hi = -FLT_MAX;
            #pragma unroll
            for (int w = 0; w < 16; ++w) {
                s += wsum[w]; lo = fminf(lo, wmn[w]); hi = fmaxf(hi, wmx[w]);
            }
            const float stdv = s * (1.0f / 1024.0f);
            const float left  = lo / stdv;
            const float right = hi / stdv;
            const float bw = 1.06f * 0.28717458874925877f;     // mean(std(m)) == 1
            const float delta = (right - left) * (1.0f / 512.0f);
            const float gstep = (right - left) * (1.0f / 511.0f);
            const float divisor = 2.5066282746310002f * bw;
            const float cpos = (0.5f / (bw * bw)) * 1.4426950408889634f;
            const float kf = sqrtf(cpos);          // arg = -(k*x - k*p)^2
            csh[0] = left;
            csh[1] = gstep;
            csh[2] = kf;
            csh[3] = (1.0f / stdv) * kf;           // xscale
            csh[4] = delta * 0.5f / divisor;       // final scale
        }
    }
    __syncthreads();
    const float left = csh[0], gstep = csh[1], kf = csh[2], xscale = csh[3];

    // ---- stage samples ----
    #pragma unroll
    for (int k = t; k < 2048; k += 1024) {
        const int e2 = k >> 9, s2 = k & 511;
        xs[e2][s2] = PT[((size_t)(((e2 << 3) + l) * 32 + f) << 9) + s2] * xscale;
    }
    __syncthreads();

    // ---- KDE: thread = (env-half h, grid point g) ----
    const int h = t >> 9, g = t & 511;
    const float p = fmaf((float)g, gstep, left) * kf;
    #pragma unroll
    for (int ei = 0; ei < 2; ++ei) {
        const int e = (h << 1) + ei;
        const int len = dlen[(e << 3) + l];        // wave-uniform
        const float* __restrict__ x = xs[e];
        float a0 = 0.f, a1 = 0.f, a2 = 0.f, a3 = 0.f;
        float a4 = 0.f, a5 = 0.f, a6 = 0.f, a7 = 0.f;
        int s = 0;
        for (; s + 8 <= len; s += 8) {
            const float4 v0 = *reinterpret_cast<const float4*>(&x[s]);
            const float4 v1 = *reinterpret_cast<const float4*>(&x[s + 4]);
            const float d0 = v0.x - p, d1 = v0.y - p, d2 = v0.z - p, d3 = v0.w - p;
            const float d4 = v1.x - p, d5 = v1.y - p, d6 = v1.z - p, d7 = v1.w - p;
            a0 += fast_exp2(-(d0 * d0));
            a1 += fast_exp2(-(d1 * d1));
            a2 += fast_exp2(-(d2 * d2));
            a3 += fast_exp2(-(d3 * d3));
            a4 += fast_exp2(-(d4 * d4));
            a5 += fast_exp2(-(d5 * d5));
            a6 += fast_exp2(-(d6 * d6));
            a7 += fast_exp2(-(d7 * d7));
        }
        for (; s < len; ++s) {
            const float d = x[s] - p;
            a0 += fast_exp2(-(d * d));
        }
        red[e][g] = (((a0 + a1) + (a2 + a3)) + ((a4 + a5) + (a6 + a7))) / (float)len;
    }
    __syncthreads();

    // ---- pairwise |diff| summed over g, all in-block ----
    if (t < 512) {
        const float r0 = red[0][t], r1 = red[1][t], r2 = red[2][t], r3 = red[3][t];
        float pr[6];
        pr[0] = fabsf(r0 - r1);
        pr[1] = fabsf(r0 - r2);
        pr[2] = fabsf(r0 - r3);
        pr[3] = fabsf(r1 - r2);
        pr[4] = fabsf(r1 - r3);
        pr[5] = fabsf(r2 - r3);
        #pragma unroll
        for (int pi = 0; pi < 6; ++pi) {
            float v = pr[pi];
            #pragma unroll
            for (int off = 32; off >= 1; off >>= 1) v += __shfl_xor(v, off, 64);
            if ((t & 63) == 0) wred[t >> 6][pi] = v;
        }
    }
    __syncthreads();
    if (t == 0) {
        const float scale = csh[4];
        float v[6];
        #pragma unroll
        for (int pi = 0; pi < 6; ++pi) {
            float sm = 0.f;
            #pragma unroll
            for (int w = 0; w < 8; ++w) sm += wred[w][pi];
            v[pi] = sm * scale;
        }
        float testv = v[0];
        #pragma unroll
        for (int pi = 1; pi < 6; ++pi) testv = fmaxf(testv, v[pi]);
        const float trainv = fmaxf(fmaxf(v[0], v[1]), v[3]);  // pairs (0,1),(0,2),(1,2)
        out[lf] = trainv;
        out[256 + lf] = testv;
        __threadfence();   // make out[] visible device-wide before the atomic
        const int old = __hip_atomic_fetch_add(counter, 1, __ATOMIC_ACQ_REL,
                                               __HIP_MEMORY_SCOPE_AGENT);
        lastf = (old == 255);
    }
    __syncthreads();

    // ---- last finished block computes the two scalar outputs ----
    if (lastf && t < 64) {
        const int ff = t & 31;
        const int base = (t >= 32) ? 256 : 0;      // lanes 0-31: train, 32-63: test
        float m = -FLT_MAX;
        #pragma unroll
        for (int ll = 0; ll < 8; ++ll) {
            const float val = __hip_atomic_load(&out[base + ll * 32 + ff],
                                                __ATOMIC_RELAXED, __HIP_MEMORY_SCOPE_AGENT);
            m = fmaxf(m, val);
        }
        #pragma unroll
        for (int off = 16; off >= 1; off >>= 1) m += __shfl_xor(m, off, 32);
        if (ff == 0) out[512 + (base ? 1 : 0)] = m * (1.0f / 32.0f);
    }
}

extern "C" void kernel_launch(void* const* d_in, const int* in_sizes, int n_in,
                              void* d_out, int out_size, void* d_ws, size_t ws_size,
                              hipStream_t stream) {
    (void)in_sizes; (void)n_in; (void)out_size; (void)ws_size;
    const float* matrix = (const float*)d_in[0];
    const float* params = (const float*)d_in[1];
    const int*   dlen   = (const int*)d_in[2];
    float* out = (float*)d_out;
    float* ws  = (float*)d_ws;
    float* PT   = ws + PT_OFF;
    float* sxg  = ws + SX_OFF;
    float* sxxg = ws + SXX_OFF;
    float* minp = ws + MIN_OFF;
    float* maxp = ws + MAX_OFF;
    int*   cnt  = (int*)(ws + CNT_OFF);

    hipLaunchKernelGGL(stage_prep, dim3(256), dim3(256), 0, stream,
                       matrix, params, PT, sxg, sxxg, minp, maxp, cnt);
    hipLaunchKernelGGL(stage_kde2, dim3(256), dim3(1024), 0, stream,
                       PT, sxg, sxxg, minp, maxp, dlen, cnt, out);
}

// Round 6
// 101.552 us; speedup vs baseline: 1.0074x; 1.0058x over previous
//
#include <hip/hip_runtime.h>
#include <float.h>

// E=4, L=8, S=512, F=32, G=512.

#if __has_builtin(__builtin_amdgcn_exp2f)
__device__ __forceinline__ float fast_exp2(float x) { return __builtin_amdgcn_exp2f(x); }
#else
__device__ __forceinline__ float fast_exp2(float x) { return exp2f(x); }
#endif

// ---- workspace layout (float offsets) ----
#define PT_OFF    0        // proj^T [E][L][F][S] = 524288 floats (unscaled)
#define SX_OFF    524288   // [256 blk][32 f] sum(x)
#define SXX_OFF   532480   // [256 blk][32 f] sum(x^2)
#define MIN_OFF   540672   // [256] per-block min
#define MAX_OFF   540928   // [256] per-block max
#define CNT_OFF   541184   // completion counter (int)

// ---------- K1: proj^T + std partials + min/max (known-good, absmax 0.0) ----------
__global__ __launch_bounds__(256) void stage_prep(const float* __restrict__ matrix,
                                                  const float* __restrict__ params,
                                                  float* __restrict__ PT,
                                                  float* __restrict__ sxg,
                                                  float* __restrict__ sxxg,
                                                  float* __restrict__ minp,
                                                  float* __restrict__ maxp,
                                                  int* __restrict__ counter) {
    __shared__ float M[64][33];    // +1 pad: proj pass reads column-wise
    __shared__ float Pm[32][32];
    __shared__ float sxr[8][32], sxxr[8][32];
    __shared__ float rmin[4], rmax[4];
    const int bid = blockIdx.x;        // (e*8+l)*8 + stile
    const int s0 = (bid & 7) << 6;
    const int el = bid >> 3;
    const int t = threadIdx.x;
    if (bid == 0 && t == 0) *counter = 0;   // reset for K2's last-block trick
    {
        const float4 v = reinterpret_cast<const float4*>(params)[t];
        const int base = t << 2;
        Pm[base >> 5][base & 31]       = v.x;
        Pm[base >> 5][(base & 31) + 1] = v.y;
        Pm[base >> 5][(base & 31) + 2] = v.z;
        Pm[base >> 5][(base & 31) + 3] = v.w;
    }
    const float4* mb4 = reinterpret_cast<const float4*>(matrix + (size_t)(el * 512 + s0) * 32);
    #pragma unroll
    for (int k = t; k < 512; k += 256) {
        const float4 v = mb4[k];
        const int base = k << 2;
        M[base >> 5][base & 31]       = v.x;
        M[base >> 5][(base & 31) + 1] = v.y;
        M[base >> 5][(base & 31) + 2] = v.z;
        M[base >> 5][(base & 31) + 3] = v.w;
    }
    __syncthreads();
    {
        const int f = t & 31, r = t >> 5;
        float sx = 0.f, sxx = 0.f;
        #pragma unroll
        for (int k = 0; k < 8; ++k) {
            float v = M[r * 8 + k][f];
            sx += v; sxx += v * v;
        }
        sxr[r][f] = sx; sxxr[r][f] = sxx;
    }
    const int s = t & 63;
    const int g0 = t >> 6;
    float lmin = FLT_MAX, lmax = -FLT_MAX;
    #pragma unroll
    for (int pass = 0; pass < 8; ++pass) {
        const int g = (pass << 2) + g0;
        float acc = 0.f;
        #pragma unroll
        for (int fp = 0; fp < 32; ++fp) acc += M[s][fp] * Pm[fp][g];
        lmin = fminf(lmin, acc);
        lmax = fmaxf(lmax, acc);
        PT[(size_t)(el * 32 + g) * 512 + s0 + s] = acc;
    }
    #pragma unroll
    for (int off = 32; off >= 1; off >>= 1) {
        lmin = fminf(lmin, __shfl_xor(lmin, off, 64));
        lmax = fmaxf(lmax, __shfl_xor(lmax, off, 64));
    }
    if ((t & 63) == 0) { rmin[t >> 6] = lmin; rmax[t >> 6] = lmax; }
    __syncthreads();
    if (t < 32) {
        float a = 0.f, b = 0.f;
        #pragma unroll
        for (int r = 0; r < 8; ++r) { a += sxr[r][t]; b += sxxr[r][t]; }
        sxg[bid * 32 + t] = a;
        sxxg[bid * 32 + t] = b;
    }
    if (t == 0) {
        minp[bid] = fminf(fminf(rmin[0], rmin[1]), fminf(rmin[2], rmin[3]));
        maxp[bid] = fmaxf(fmaxf(rmax[0], rmax[1]), fmaxf(rmax[2], rmax[3]));
    }
}

// ---------- K2: consts + KDE (P=4 grid points/thread) + pair L1 + outputs ----------
// 256 blocks = one per (l,f); 512 threads = (e = t>>7, gl = t&127).
// Each thread owns 4 grid points {gl+128j}: one ds_read_b128 (4 samples)
// feeds 16 exps — 4x less LDS-broadcast traffic than 1 point/thread.
__global__ __launch_bounds__(512) void stage_kde2(const float* __restrict__ PT,
                                                  const float* __restrict__ sxg,
                                                  const float* __restrict__ sxxg,
                                                  const float* __restrict__ minp,
                                                  const float* __restrict__ maxp,
                                                  const int* __restrict__ dlen,
                                                  int* __restrict__ counter,
                                                  float* __restrict__ out) {
    __shared__ __align__(16) float xs[4][512];
    __shared__ float red[4][512];
    __shared__ float wsum[8], wmn[8], wmx[8];
    __shared__ float wred[8][6];
    __shared__ float csh[6];
    __shared__ int lastf;
    const int t = threadIdx.x;
    const int lf = blockIdx.x;
    const int l = lf >> 5, f = lf & 31;

    // ---- consts: every block redundantly reduces K1's tiny partials ----
    {
        float sf = 0.f;
        #pragma unroll
        for (int tr = t; tr < 1024; tr += 512) {     // (e,l,f) triples
            const int el = tr >> 5, fc = tr & 31;
            const int base = el * 256 + fc;
            float Sx = 0.f, Sxx = 0.f;
            #pragma unroll
            for (int tile = 0; tile < 8; ++tile) { Sx += sxg[base + tile * 32]; Sxx += sxxg[base + tile * 32]; }
            const float mean = Sx * (1.0f / 512.0f);
            const float var = (Sxx - Sx * mean) * (1.0f / 511.0f);   // ddof=1
            sf += sqrtf(fmaxf(var, 0.f));
        }
        float mn = (t < 256) ? minp[t] : FLT_MAX;
        float mx = (t < 256) ? maxp[t] : -FLT_MAX;
        #pragma unroll
        for (int off = 32; off >= 1; off >>= 1) {
            sf += __shfl_xor(sf, off, 64);
            mn = fminf(mn, __shfl_xor(mn, off, 64));
            mx = fmaxf(mx, __shfl_xor(mx, off, 64));
        }
        if ((t & 63) == 0) { wsum[t >> 6] = sf; wmn[t >> 6] = mn; wmx[t >> 6] = mx; }
        __syncthreads();
        if (t == 0) {
            float s = 0.f, lo = FLT_MAX, hi = -FLT_MAX;
            #pragma unroll
            for (int w = 0; w < 8; ++w) {
                s += wsum[w]; lo = fminf(lo, wmn[w]); hi = fmaxf(hi, wmx[w]);
            }
            const float stdv = s * (1.0f / 1024.0f);
            const float left  = lo / stdv;
            const float right = hi / stdv;
            const float bw = 1.06f * 0.28717458874925877f;     // mean(std(m)) == 1
            const float delta = (right - left) * (1.0f / 512.0f);
            const float gstep = (right - left) * (1.0f / 511.0f);
            const float divisor = 2.5066282746310002f * bw;
            const float cpos = (0.5f / (bw * bw)) * 1.4426950408889634f;
            const float kf = sqrtf(cpos);          // arg = -(k*x - k*p)^2
            csh[0] = left;
            csh[1] = gstep;
            csh[2] = kf;
            csh[3] = (1.0f / stdv) * kf;           // xscale
            csh[4] = delta * 0.5f / divisor;       // final scale
        }
    }
    __syncthreads();
    const float left = csh[0], gstep = csh[1], kf = csh[2], xscale = csh[3];

    // ---- stage samples ----
    #pragma unroll
    for (int k = t; k < 2048; k += 512) {
        const int e2 = k >> 9, s2 = k & 511;
        xs[e2][s2] = PT[((size_t)(((e2 << 3) + l) * 32 + f) << 9) + s2] * xscale;
    }
    __syncthreads();

    // ---- KDE: thread = (env e, base grid point gl), 4 grid points gl+128j ----
    const int e = t >> 7, gl = t & 127;
    const int len = dlen[(e << 3) + l];            // wave-uniform
    float p[4];
    #pragma unroll
    for (int j = 0; j < 4; ++j)
        p[j] = fmaf((float)(gl + 128 * j), gstep, left) * kf;
    const float* __restrict__ x = xs[e];
    float acc[4][2];
    #pragma unroll
    for (int j = 0; j < 4; ++j) { acc[j][0] = 0.f; acc[j][1] = 0.f; }
    const int len4 = len & ~3;
    int s = 0;
    if (len4 > 0) {
        float4 v = *reinterpret_cast<const float4*>(&x[0]);
        for (s = 4; s < len4; s += 4) {
            const float4 nv = *reinterpret_cast<const float4*>(&x[s]);  // prefetch
            #pragma unroll
            for (int j = 0; j < 4; ++j) {
                const float d0 = v.x - p[j], d1 = v.y - p[j];
                const float d2 = v.z - p[j], d3 = v.w - p[j];
                acc[j][0] += fast_exp2(-(d0 * d0));
                acc[j][1] += fast_exp2(-(d1 * d1));
                acc[j][0] += fast_exp2(-(d2 * d2));
                acc[j][1] += fast_exp2(-(d3 * d3));
            }
            v = nv;
        }
        #pragma unroll
        for (int j = 0; j < 4; ++j) {
            const float d0 = v.x - p[j], d1 = v.y - p[j];
            const float d2 = v.z - p[j], d3 = v.w - p[j];
            acc[j][0] += fast_exp2(-(d0 * d0));
            acc[j][1] += fast_exp2(-(d1 * d1));
            acc[j][0] += fast_exp2(-(d2 * d2));
            acc[j][1] += fast_exp2(-(d3 * d3));
        }
        s = len4;
    }
    for (; s < len; ++s) {
        const float xv = x[s];
        #pragma unroll
        for (int j = 0; j < 4; ++j) {
            const float d = xv - p[j];
            acc[j][0] += fast_exp2(-(d * d));
        }
    }
    const float inv_len = 1.0f / (float)len;
    #pragma unroll
    for (int j = 0; j < 4; ++j)
        red[e][gl + 128 * j] = (acc[j][0] + acc[j][1]) * inv_len;
    __syncthreads();

    // ---- pairwise |diff| summed over g, all in-block ----
    {
        const float r0 = red[0][t], r1 = red[1][t], r2 = red[2][t], r3 = red[3][t];
        float pr[6];
        pr[0] = fabsf(r0 - r1);
        pr[1] = fabsf(r0 - r2);
        pr[2] = fabsf(r0 - r3);
        pr[3] = fabsf(r1 - r2);
        pr[4] = fabsf(r1 - r3);
        pr[5] = fabsf(r2 - r3);
        #pragma unroll
        for (int pi = 0; pi < 6; ++pi) {
            float v = pr[pi];
            #pragma unroll
            for (int off = 32; off >= 1; off >>= 1) v += __shfl_xor(v, off, 64);
            if ((t & 63) == 0) wred[t >> 6][pi] = v;
        }
    }
    __syncthreads();
    if (t == 0) {
        const float scale = csh[4];
        float v[6];
        #pragma unroll
        for (int pi = 0; pi < 6; ++pi) {
            float sm = 0.f;
            #pragma unroll
            for (int w = 0; w < 8; ++w) sm += wred[w][pi];
            v[pi] = sm * scale;
        }
        float testv = v[0];
        #pragma unroll
        for (int pi = 1; pi < 6; ++pi) testv = fmaxf(testv, v[pi]);
        const float trainv = fmaxf(fmaxf(v[0], v[1]), v[3]);  // pairs (0,1),(0,2),(1,2)
        out[lf] = trainv;
        out[256 + lf] = testv;
        __threadfence();   // make out[] visible device-wide before the atomic
        const int old = __hip_atomic_fetch_add(counter, 1, __ATOMIC_ACQ_REL,
                                               __HIP_MEMORY_SCOPE_AGENT);
        lastf = (old == 255);
    }
    __syncthreads();

    // ---- last finished block computes the two scalar outputs ----
    if (lastf && t < 64) {
        const int ff = t & 31;
        const int base = (t >= 32) ? 256 : 0;      // lanes 0-31: train, 32-63: test
        float m = -FLT_MAX;
        #pragma unroll
        for (int ll = 0; ll < 8; ++ll) {
            const float val = __hip_atomic_load(&out[base + ll * 32 + ff],
                                                __ATOMIC_RELAXED, __HIP_MEMORY_SCOPE_AGENT);
            m = fmaxf(m, val);
        }
        #pragma unroll
        for (int off = 16; off >= 1; off >>= 1) m += __shfl_xor(m, off, 32);
        if (ff == 0) out[512 + (base ? 1 : 0)] = m * (1.0f / 32.0f);
    }
}

extern "C" void kernel_launch(void* const* d_in, const int* in_sizes, int n_in,
                              void* d_out, int out_size, void* d_ws, size_t ws_size,
                              hipStream_t stream) {
    (void)in_sizes; (void)n_in; (void)out_size; (void)ws_size;
    const float* matrix = (const float*)d_in[0];
    const float* params = (const float*)d_in[1];
    const int*   dlen   = (const int*)d_in[2];
    float* out = (float*)d_out;
    float* ws  = (float*)d_ws;
    float* PT   = ws + PT_OFF;
    float* sxg  = ws + SX_OFF;
    float* sxxg = ws + SXX_OFF;
    float* minp = ws + MIN_OFF;
    float* maxp = ws + MAX_OFF;
    int*   cnt  = (int*)(ws + CNT_OFF);

    hipLaunchKernelGGL(stage_prep, dim3(256), dim3(256), 0, stream,
                       matrix, params, PT, sxg, sxxg, minp, maxp, cnt);
    hipLaunchKernelGGL(stage_kde2, dim3(256), dim3(512), 0, stream,
                       PT, sxg, sxxg, minp, maxp, dlen, cnt, out);
}

// Round 7
// 93.911 us; speedup vs baseline: 1.0893x; 1.0814x over previous
//
#include <hip/hip_runtime.h>
#include <float.h>

// E=4, L=8, S=512, F=32, G=512.

#if __has_builtin(__builtin_amdgcn_exp2f)
__device__ __forceinline__ float fast_exp2(float x) { return __builtin_amdgcn_exp2f(x); }
#else
__device__ __forceinline__ float fast_exp2(float x) { return exp2f(x); }
#endif

#define CULL_R 4.0f   // scaled units: dropped terms <= 2^-16 each

// ---- workspace layout (float offsets) ----
#define PT_OFF    0        // proj^T [E][L][F][S] = 524288 floats (unscaled)
#define SX_OFF    524288   // [256 blk][32 f] sum(x)
#define SXX_OFF   532480   // [256 blk][32 f] sum(x^2)
#define MIN_OFF   540672   // [256] per-block min
#define MAX_OFF   540928   // [256] per-block max
#define CNT_OFF   541184   // completion counter (int)

// ---------- K1: proj^T + std partials + min/max (known-good, absmax 0.0) ----------
__global__ __launch_bounds__(256) void stage_prep(const float* __restrict__ matrix,
                                                  const float* __restrict__ params,
                                                  float* __restrict__ PT,
                                                  float* __restrict__ sxg,
                                                  float* __restrict__ sxxg,
                                                  float* __restrict__ minp,
                                                  float* __restrict__ maxp,
                                                  int* __restrict__ counter) {
    __shared__ float M[64][33];    // +1 pad: proj pass reads column-wise
    __shared__ float Pm[32][32];
    __shared__ float sxr[8][32], sxxr[8][32];
    __shared__ float rmin[4], rmax[4];
    const int bid = blockIdx.x;        // (e*8+l)*8 + stile
    const int s0 = (bid & 7) << 6;
    const int el = bid >> 3;
    const int t = threadIdx.x;
    if (bid == 0 && t == 0) *counter = 0;   // reset for K2's last-block trick
    {
        const float4 v = reinterpret_cast<const float4*>(params)[t];
        const int base = t << 2;
        Pm[base >> 5][base & 31]       = v.x;
        Pm[base >> 5][(base & 31) + 1] = v.y;
        Pm[base >> 5][(base & 31) + 2] = v.z;
        Pm[base >> 5][(base & 31) + 3] = v.w;
    }
    const float4* mb4 = reinterpret_cast<const float4*>(matrix + (size_t)(el * 512 + s0) * 32);
    #pragma unroll
    for (int k = t; k < 512; k += 256) {
        const float4 v = mb4[k];
        const int base = k << 2;
        M[base >> 5][base & 31]       = v.x;
        M[base >> 5][(base & 31) + 1] = v.y;
        M[base >> 5][(base & 31) + 2] = v.z;
        M[base >> 5][(base & 31) + 3] = v.w;
    }
    __syncthreads();
    {
        const int f = t & 31, r = t >> 5;
        float sx = 0.f, sxx = 0.f;
        #pragma unroll
        for (int k = 0; k < 8; ++k) {
            float v = M[r * 8 + k][f];
            sx += v; sxx += v * v;
        }
        sxr[r][f] = sx; sxxr[r][f] = sxx;
    }
    const int s = t & 63;
    const int g0 = t >> 6;
    float lmin = FLT_MAX, lmax = -FLT_MAX;
    #pragma unroll
    for (int pass = 0; pass < 8; ++pass) {
        const int g = (pass << 2) + g0;
        float acc = 0.f;
        #pragma unroll
        for (int fp = 0; fp < 32; ++fp) acc += M[s][fp] * Pm[fp][g];
        lmin = fminf(lmin, acc);
        lmax = fmaxf(lmax, acc);
        PT[(size_t)(el * 32 + g) * 512 + s0 + s] = acc;
    }
    #pragma unroll
    for (int off = 32; off >= 1; off >>= 1) {
        lmin = fminf(lmin, __shfl_xor(lmin, off, 64));
        lmax = fmaxf(lmax, __shfl_xor(lmax, off, 64));
    }
    if ((t & 63) == 0) { rmin[t >> 6] = lmin; rmax[t >> 6] = lmax; }
    __syncthreads();
    if (t < 32) {
        float a = 0.f, b = 0.f;
        #pragma unroll
        for (int r = 0; r < 8; ++r) { a += sxr[r][t]; b += sxxr[r][t]; }
        sxg[bid * 32 + t] = a;
        sxxg[bid * 32 + t] = b;
    }
    if (t == 0) {
        minp[bid] = fminf(fminf(rmin[0], rmin[1]), fminf(rmin[2], rmin[3]));
        maxp[bid] = fmaxf(fmaxf(rmax[0], rmax[1]), fmaxf(rmax[2], rmax[3]));
    }
}

// ---------- K2: consts + bucket-sort + culled KDE + pair L1 + outputs ----------
// 256 blocks = one per (l,f); 512 threads = (e = t>>7, gl = t&127), 4 grid
// points per thread {gl+128j}. Samples are counting-sorted by value into 64
// buckets; each wave processes only the wave-uniform contiguous sorted range
// within +-CULL_R of its p-range (dropped terms <= 2^-16 each).
__global__ __launch_bounds__(512) void stage_kde2(const float* __restrict__ PT,
                                                  const float* __restrict__ sxg,
                                                  const float* __restrict__ sxxg,
                                                  const float* __restrict__ minp,
                                                  const float* __restrict__ maxp,
                                                  const int* __restrict__ dlen,
                                                  int* __restrict__ counter,
                                                  float* __restrict__ out) {
    __shared__ __align__(16) float bufA[4][512];   // scaled samples, later red[]
    __shared__ __align__(16) float bufS[4][512];   // bucket-sorted samples
    __shared__ int hist[4][64];                    // histogram, then scatter cursor
    __shared__ int startb[4][65];                  // bucket prefix starts
    __shared__ int lensh[4];
    __shared__ float wsum[8], wmn[8], wmx[8];
    __shared__ float wred[8][6];
    __shared__ float csh[8];
    __shared__ int lastf;
    const int t = threadIdx.x;
    const int lf = blockIdx.x;
    const int l = lf >> 5, f = lf & 31;

    if (t < 4) lensh[t] = dlen[(t << 3) + l];

    // ---- consts: every block redundantly reduces K1's tiny partials ----
    {
        float sf = 0.f;
        #pragma unroll
        for (int tr = t; tr < 1024; tr += 512) {     // (e,l,f) triples
            const int el = tr >> 5, fc = tr & 31;
            const int base = el * 256 + fc;
            float Sx = 0.f, Sxx = 0.f;
            #pragma unroll
            for (int tile = 0; tile < 8; ++tile) { Sx += sxg[base + tile * 32]; Sxx += sxxg[base + tile * 32]; }
            const float mean = Sx * (1.0f / 512.0f);
            const float var = (Sxx - Sx * mean) * (1.0f / 511.0f);   // ddof=1
            sf += sqrtf(fmaxf(var, 0.f));
        }
        float mn = (t < 256) ? minp[t] : FLT_MAX;
        float mx = (t < 256) ? maxp[t] : -FLT_MAX;
        #pragma unroll
        for (int off = 32; off >= 1; off >>= 1) {
            sf += __shfl_xor(sf, off, 64);
            mn = fminf(mn, __shfl_xor(mn, off, 64));
            mx = fmaxf(mx, __shfl_xor(mx, off, 64));
        }
        if ((t & 63) == 0) { wsum[t >> 6] = sf; wmn[t >> 6] = mn; wmx[t >> 6] = mx; }
        __syncthreads();
        if (t == 0) {
            float s = 0.f, lo = FLT_MAX, hi = -FLT_MAX;
            #pragma unroll
            for (int w = 0; w < 8; ++w) {
                s += wsum[w]; lo = fminf(lo, wmn[w]); hi = fmaxf(hi, wmx[w]);
            }
            const float stdv = s * (1.0f / 1024.0f);
            const float left  = lo / stdv;
            const float right = hi / stdv;
            const float bw = 1.06f * 0.28717458874925877f;     // mean(std(m)) == 1
            const float delta = (right - left) * (1.0f / 512.0f);
            const float gstep = (right - left) * (1.0f / 511.0f);
            const float divisor = 2.5066282746310002f * bw;
            const float cpos = (0.5f / (bw * bw)) * 1.4426950408889634f;
            const float kf = sqrtf(cpos);          // arg = -(k*x - k*p)^2
            const float leftk = left * kf, rightk = right * kf;
            csh[0] = leftk;
            csh[1] = gstep * kf;                   // grid step, scaled
            csh[2] = (1.0f / stdv) * kf;           // xscale
            csh[3] = delta * 0.5f / divisor;       // final scale
            csh[4] = leftk - 1e-3f;                // bucket lo
            csh[5] = 64.0f / (rightk - leftk + 2e-3f);  // bucket binv
        }
    }
    __syncthreads();
    const float leftk = csh[0], gstepk = csh[1], xscale = csh[2];
    const float blo_ = csh[4], binv_ = csh[5];

    // ---- stage scaled samples + zero histogram ----
    #pragma unroll
    for (int k = t; k < 2048; k += 512) {
        const int e2 = k >> 9, s2 = k & 511;
        bufA[e2][s2] = PT[((size_t)(((e2 << 3) + l) * 32 + f) << 9) + s2] * xscale;
    }
    if (t < 256) hist[t >> 6][t & 63] = 0;
    __syncthreads();

    // ---- histogram (only valid samples s < len) ----
    #pragma unroll
    for (int k = t; k < 2048; k += 512) {
        const int e2 = k >> 9, s2 = k & 511;
        if (s2 < lensh[e2]) {
            int b = (int)((bufA[e2][s2] - blo_) * binv_);
            b = max(0, min(63, b));
            atomicAdd(&hist[e2][b], 1);
        }
    }
    __syncthreads();
    if (t < 4) {   // serial exclusive scan per env (64 adds)
        int acc = 0;
        startb[t][0] = 0;
        for (int b = 0; b < 64; ++b) { acc += hist[t][b]; startb[t][b + 1] = acc; }
    }
    __syncthreads();
    if (t < 256) hist[t >> 6][t & 63] = startb[t >> 6][t & 63];   // cursor init
    __syncthreads();
    // ---- scatter into bucket-sorted array ----
    #pragma unroll
    for (int k = t; k < 2048; k += 512) {
        const int e2 = k >> 9, s2 = k & 511;
        if (s2 < lensh[e2]) {
            const float X = bufA[e2][s2];
            int b = (int)((X - blo_) * binv_);
            b = max(0, min(63, b));
            const int pos = atomicAdd(&hist[e2][b], 1);
            bufS[e2][pos] = X;
        }
    }
    __syncthreads();   // bufA (unsorted) now dead -> reused as red[]

    // ---- culled KDE: thread = (e, gl), 4 grid points gl+128j ----
    {
        const int e = t >> 7, gl = t & 127;
        const int len = lensh[e];
        const float inv_len = 1.0f / (float)len;
        const int glA = gl & 64;                   // wave-uniform base (0 or 64)
        const float* __restrict__ x = bufS[e];
        #pragma unroll
        for (int j = 0; j < 4; ++j) {
            const int jg = gl + 128 * j;
            const float P = fmaf((float)jg, gstepk, leftk);
            // wave-uniform window over the wave's 64 consecutive grid points
            const float Plo = fmaf((float)(glA + 128 * j), gstepk, leftk) - CULL_R;
            const float Phi = fmaf((float)(glA + 63 + 128 * j), gstepk, leftk) + CULL_R;
            int blo = (int)((Plo - blo_) * binv_); blo = max(0, min(63, blo));
            int bhi = (int)((Phi - blo_) * binv_); bhi = max(0, min(63, bhi));
            const int slo = startb[e][blo] & ~3;   // align down for float4
            const int shi = startb[e][bhi + 1];
            float a0 = 0.f, a1 = 0.f, a2 = 0.f, a3 = 0.f;
            int s = slo;
            for (; s + 4 <= shi; s += 4) {
                const float4 v = *reinterpret_cast<const float4*>(&x[s]);
                const float d0 = v.x - P, d1 = v.y - P;
                const float d2 = v.z - P, d3 = v.w - P;
                a0 += fast_exp2(-(d0 * d0));
                a1 += fast_exp2(-(d1 * d1));
                a2 += fast_exp2(-(d2 * d2));
                a3 += fast_exp2(-(d3 * d3));
            }
            for (; s < shi; ++s) {
                const float d = x[s] - P;
                a0 += fast_exp2(-(d * d));
            }
            bufA[e][jg] = ((a0 + a1) + (a2 + a3)) * inv_len;   // red overlay
        }
    }
    __syncthreads();

    // ---- pairwise |diff| summed over g, all in-block ----
    {
        const float r0 = bufA[0][t], r1 = bufA[1][t], r2 = bufA[2][t], r3 = bufA[3][t];
        float pr[6];
        pr[0] = fabsf(r0 - r1);
        pr[1] = fabsf(r0 - r2);
        pr[2] = fabsf(r0 - r3);
        pr[3] = fabsf(r1 - r2);
        pr[4] = fabsf(r1 - r3);
        pr[5] = fabsf(r2 - r3);
        #pragma unroll
        for (int pi = 0; pi < 6; ++pi) {
            float v = pr[pi];
            #pragma unroll
            for (int off = 32; off >= 1; off >>= 1) v += __shfl_xor(v, off, 64);
            if ((t & 63) == 0) wred[t >> 6][pi] = v;
        }
    }
    __syncthreads();
    if (t == 0) {
        const float scale = csh[3];
        float v[6];
        #pragma unroll
        for (int pi = 0; pi < 6; ++pi) {
            float sm = 0.f;
            #pragma unroll
            for (int w = 0; w < 8; ++w) sm += wred[w][pi];
            v[pi] = sm * scale;
        }
        float testv = v[0];
        #pragma unroll
        for (int pi = 1; pi < 6; ++pi) testv = fmaxf(testv, v[pi]);
        const float trainv = fmaxf(fmaxf(v[0], v[1]), v[3]);  // pairs (0,1),(0,2),(1,2)
        out[lf] = trainv;
        out[256 + lf] = testv;
        __threadfence();   // make out[] visible device-wide before the atomic
        const int old = __hip_atomic_fetch_add(counter, 1, __ATOMIC_ACQ_REL,
                                               __HIP_MEMORY_SCOPE_AGENT);
        lastf = (old == 255);
    }
    __syncthreads();

    // ---- last finished block computes the two scalar outputs ----
    if (lastf && t < 64) {
        const int ff = t & 31;
        const int base = (t >= 32) ? 256 : 0;      // lanes 0-31: train, 32-63: test
        float m = -FLT_MAX;
        #pragma unroll
        for (int ll = 0; ll < 8; ++ll) {
            const float val = __hip_atomic_load(&out[base + ll * 32 + ff],
                                                __ATOMIC_RELAXED, __HIP_MEMORY_SCOPE_AGENT);
            m = fmaxf(m, val);
        }
        #pragma unroll
        for (int off = 16; off >= 1; off >>= 1) m += __shfl_xor(m, off, 32);
        if (ff == 0) out[512 + (base ? 1 : 0)] = m * (1.0f / 32.0f);
    }
}

extern "C" void kernel_launch(void* const* d_in, const int* in_sizes, int n_in,
                              void* d_out, int out_size, void* d_ws, size_t ws_size,
                              hipStream_t stream) {
    (void)in_sizes; (void)n_in; (void)out_size; (void)ws_size;
    const float* matrix = (const float*)d_in[0];
    const float* params = (const float*)d_in[1];
    const int*   dlen   = (const int*)d_in[2];
    float* out = (float*)d_out;
    float* ws  = (float*)d_ws;
    float* PT   = ws + PT_OFF;
    float* sxg  = ws + SX_OFF;
    float* sxxg = ws + SXX_OFF;
    float* minp = ws + MIN_OFF;
    float* maxp = ws + MAX_OFF;
    int*   cnt  = (int*)(ws + CNT_OFF);

    hipLaunchKernelGGL(stage_prep, dim3(256), dim3(256), 0, stream,
                       matrix, params, PT, sxg, sxxg, minp, maxp, cnt);
    hipLaunchKernelGGL(stage_kde2, dim3(256), dim3(512), 0, stream,
                       PT, sxg, sxxg, minp, maxp, dlen, cnt, out);
}

// Round 8
// 88.304 us; speedup vs baseline: 1.1585x; 1.0635x over previous
//
#include <hip/hip_runtime.h>
#include <float.h>

// E=4, L=8, S=512, F=32, G=512 fine grid, GC=256 coarse grid (h = 2 fine steps).

#if __has_builtin(__builtin_amdgcn_exp2f)
__device__ __forceinline__ float fast_exp2(float x) { return __builtin_amdgcn_exp2f(x); }
#else
__device__ __forceinline__ float fast_exp2(float x) { return exp2f(x); }
#endif

#define CULL_R 3.25f   // scaled units: dropped terms <= 2^-10.6 each

// ---- workspace layout (float offsets) ----
#define PT_OFF    0        // proj^T [E][L][F][S] = 524288 floats (unscaled)
#define SX_OFF    524288   // [256 blk][32 f] sum(x)
#define SXX_OFF   532480   // [256 blk][32 f] sum(x^2)
#define MIN_OFF   540672   // [256] per-block min
#define MAX_OFF   540928   // [256] per-block max
#define CNT_OFF   541184   // completion counter (int)

// ---------- K1: proj^T + std partials + min/max (known-good, absmax 0.0) ----------
__global__ __launch_bounds__(256) void stage_prep(const float* __restrict__ matrix,
                                                  const float* __restrict__ params,
                                                  float* __restrict__ PT,
                                                  float* __restrict__ sxg,
                                                  float* __restrict__ sxxg,
                                                  float* __restrict__ minp,
                                                  float* __restrict__ maxp,
                                                  int* __restrict__ counter) {
    __shared__ float M[64][33];    // +1 pad: proj pass reads column-wise
    __shared__ float Pm[32][32];
    __shared__ float sxr[8][32], sxxr[8][32];
    __shared__ float rmin[4], rmax[4];
    const int bid = blockIdx.x;        // (e*8+l)*8 + stile
    const int s0 = (bid & 7) << 6;
    const int el = bid >> 3;
    const int t = threadIdx.x;
    if (bid == 0 && t == 0) *counter = 0;   // reset for K2's last-block trick
    {
        const float4 v = reinterpret_cast<const float4*>(params)[t];
        const int base = t << 2;
        Pm[base >> 5][base & 31]       = v.x;
        Pm[base >> 5][(base & 31) + 1] = v.y;
        Pm[base >> 5][(base & 31) + 2] = v.z;
        Pm[base >> 5][(base & 31) + 3] = v.w;
    }
    const float4* mb4 = reinterpret_cast<const float4*>(matrix + (size_t)(el * 512 + s0) * 32);
    #pragma unroll
    for (int k = t; k < 512; k += 256) {
        const float4 v = mb4[k];
        const int base = k << 2;
        M[base >> 5][base & 31]       = v.x;
        M[base >> 5][(base & 31) + 1] = v.y;
        M[base >> 5][(base & 31) + 2] = v.z;
        M[base >> 5][(base & 31) + 3] = v.w;
    }
    __syncthreads();
    {
        const int f = t & 31, r = t >> 5;
        float sx = 0.f, sxx = 0.f;
        #pragma unroll
        for (int k = 0; k < 8; ++k) {
            float v = M[r * 8 + k][f];
            sx += v; sxx += v * v;
        }
        sxr[r][f] = sx; sxxr[r][f] = sxx;
    }
    const int s = t & 63;
    const int g0 = t >> 6;
    float lmin = FLT_MAX, lmax = -FLT_MAX;
    #pragma unroll
    for (int pass = 0; pass < 8; ++pass) {
        const int g = (pass << 2) + g0;
        float acc = 0.f;
        #pragma unroll
        for (int fp = 0; fp < 32; ++fp) acc += M[s][fp] * Pm[fp][g];
        lmin = fminf(lmin, acc);
        lmax = fmaxf(lmax, acc);
        PT[(size_t)(el * 32 + g) * 512 + s0 + s] = acc;
    }
    #pragma unroll
    for (int off = 32; off >= 1; off >>= 1) {
        lmin = fminf(lmin, __shfl_xor(lmin, off, 64));
        lmax = fmaxf(lmax, __shfl_xor(lmax, off, 64));
    }
    if ((t & 63) == 0) { rmin[t >> 6] = lmin; rmax[t >> 6] = lmax; }
    __syncthreads();
    if (t < 32) {
        float a = 0.f, b = 0.f;
        #pragma unroll
        for (int r = 0; r < 8; ++r) { a += sxr[r][t]; b += sxxr[r][t]; }
        sxg[bid * 32 + t] = a;
        sxxg[bid * 32 + t] = b;
    }
    if (t == 0) {
        minp[bid] = fminf(fminf(rmin[0], rmin[1]), fminf(rmin[2], rmin[3]));
        maxp[bid] = fmaxf(fmaxf(rmax[0], rmax[1]), fmaxf(rmax[2], rmax[3]));
    }
}

// ---------- K2: consts + bucket-sort + culled coarse KDE + cubic interp + outputs ----------
// 256 blocks = one per (l,f); 512 threads. Coarse KDE on 256 points (h = 2 fine
// steps), wave-uniform sorted-window culling, then 4-tap Lagrange interp to the
// 512 fine points. Samples go registers -> histogram -> scatter (no staging buf).
__global__ __launch_bounds__(512) void stage_kde2(const float* __restrict__ PT,
                                                  const float* __restrict__ sxg,
                                                  const float* __restrict__ sxxg,
                                                  const float* __restrict__ minp,
                                                  const float* __restrict__ maxp,
                                                  const int* __restrict__ dlen,
                                                  int* __restrict__ counter,
                                                  float* __restrict__ out) {
    __shared__ __align__(16) float bufS[4][512];   // sorted samples, later fine red
    __shared__ float coar[4][256];                 // coarse KDE values
    __shared__ int hist[4][64];                    // histogram, then scatter cursor
    __shared__ int startb[4][65];                  // bucket prefix starts
    __shared__ int lensh[4];
    __shared__ float wsum[8], wmn[8], wmx[8];
    __shared__ float wred[8][6];
    __shared__ float csh[8];
    __shared__ int lastf;
    const int t = threadIdx.x;
    const int lf = blockIdx.x;
    const int l = lf >> 5, f = lf & 31;

    if (t < 4) lensh[t] = dlen[(t << 3) + l];
    if (t < 256) hist[t >> 6][t & 63] = 0;

    // ---- consts: every block redundantly reduces K1's tiny partials ----
    {
        float sf = 0.f;
        #pragma unroll
        for (int tr = t; tr < 1024; tr += 512) {     // (e,l,f) triples
            const int el = tr >> 5, fc = tr & 31;
            const int base = el * 256 + fc;
            float Sx = 0.f, Sxx = 0.f;
            #pragma unroll
            for (int tile = 0; tile < 8; ++tile) { Sx += sxg[base + tile * 32]; Sxx += sxxg[base + tile * 32]; }
            const float mean = Sx * (1.0f / 512.0f);
            const float var = (Sxx - Sx * mean) * (1.0f / 511.0f);   // ddof=1
            sf += sqrtf(fmaxf(var, 0.f));
        }
        float mn = (t < 256) ? minp[t] : FLT_MAX;
        float mx = (t < 256) ? maxp[t] : -FLT_MAX;
        #pragma unroll
        for (int off = 32; off >= 1; off >>= 1) {
            sf += __shfl_xor(sf, off, 64);
            mn = fminf(mn, __shfl_xor(mn, off, 64));
            mx = fmaxf(mx, __shfl_xor(mx, off, 64));
        }
        if ((t & 63) == 0) { wsum[t >> 6] = sf; wmn[t >> 6] = mn; wmx[t >> 6] = mx; }
        __syncthreads();
        if (t == 0) {
            float s = 0.f, lo = FLT_MAX, hi = -FLT_MAX;
            #pragma unroll
            for (int w = 0; w < 8; ++w) {
                s += wsum[w]; lo = fminf(lo, wmn[w]); hi = fmaxf(hi, wmx[w]);
            }
            const float stdv = s * (1.0f / 1024.0f);
            const float left  = lo / stdv;
            const float right = hi / stdv;
            const float bw = 1.06f * 0.28717458874925877f;     // mean(std(m)) == 1
            const float delta = (right - left) * (1.0f / 512.0f);
            const float gstep = (right - left) * (1.0f / 511.0f);
            const float divisor = 2.5066282746310002f * bw;
            const float cpos = (0.5f / (bw * bw)) * 1.4426950408889634f;
            const float kf = sqrtf(cpos);          // arg = -(k*x - k*p)^2
            const float leftk = left * kf, rightk = right * kf;
            csh[0] = leftk;
            csh[1] = gstep * kf;                   // fine grid step, scaled
            csh[2] = (1.0f / stdv) * kf;           // xscale
            csh[3] = delta * 0.5f / divisor;       // final scale
            csh[4] = leftk - 1e-3f;                // bucket lo
            csh[5] = 64.0f / (rightk - leftk + 2e-3f);  // bucket binv
        }
    }
    __syncthreads();
    const float leftk = csh[0], gstepk = csh[1], xscale = csh[2];
    const float blo_ = csh[4], binv_ = csh[5];

    // ---- load 4 samples/thread into registers, histogram ----
    const int e = t >> 7;                 // env owning this thread's samples & windows
    const int sbase = (t & 127) << 2;
    const int lenE = lensh[e];
    float X[4];
    int bk[4];
    {
        const size_t row = ((size_t)(((e << 3) + l) * 32 + f) << 9);
        const float4 xv = *reinterpret_cast<const float4*>(&PT[row + sbase]);
        X[0] = xv.x * xscale; X[1] = xv.y * xscale;
        X[2] = xv.z * xscale; X[3] = xv.w * xscale;
        #pragma unroll
        for (int q = 0; q < 4; ++q) {
            int b = (int)((X[q] - blo_) * binv_);
            bk[q] = max(0, min(63, b));
            if (sbase + q < lenE) atomicAdd(&hist[e][bk[q]], 1);
        }
    }
    __syncthreads();

    // ---- parallel prefix scan (one wave per env) ----
    if (t < 256) {
        const int w = t >> 6, lane = t & 63;
        const int orig = hist[w][lane];
        int v = orig;
        #pragma unroll
        for (int d = 1; d < 64; d <<= 1) {
            const int n = __shfl_up(v, d, 64);
            if (lane >= d) v += n;
        }
        startb[w][lane + 1] = v;
        if (lane == 0) startb[w][0] = 0;
        hist[w][lane] = v - orig;          // exclusive start -> scatter cursor
    }
    __syncthreads();

    // ---- scatter into value-sorted (bucketed) array ----
    #pragma unroll
    for (int q = 0; q < 4; ++q) {
        if (sbase + q < lenE) {
            const int pos = atomicAdd(&hist[e][bk[q]], 1);
            bufS[e][pos] = X[q];
        }
    }
    __syncthreads();

    // ---- culled coarse KDE: thread = (e, i0 = t&127), coarse pts i0, i0+128 ----
    {
        const int i0 = t & 127;
        const int glA = i0 & 64;           // wave-uniform chunk base (0 or 64)
        const float inv_len = 1.0f / (float)lenE;
        const float* __restrict__ x = bufS[e];
        #pragma unroll
        for (int j = 0; j < 2; ++j) {
            const int ic = i0 + 128 * j;
            const float P = fmaf((float)(2 * ic), gstepk, leftk);
            const int icA = glA + 128 * j;
            const float Plo = fmaf((float)(2 * icA), gstepk, leftk) - CULL_R;
            const float Phi = fmaf((float)(2 * (icA + 63)), gstepk, leftk) + CULL_R;
            int blo = (int)((Plo - blo_) * binv_); blo = max(0, min(63, blo));
            int bhi = (int)((Phi - blo_) * binv_); bhi = max(0, min(63, bhi));
            const int slo = startb[e][blo] & ~3;   // float4-align down
            const int shi = startb[e][bhi + 1];
            float a0 = 0.f, a1 = 0.f, a2 = 0.f, a3 = 0.f;
            int s = slo;
            if (s + 4 <= shi) {
                float4 v = *reinterpret_cast<const float4*>(&x[s]);
                s += 4;
                for (; s + 4 <= shi; s += 4) {
                    const float4 nv = *reinterpret_cast<const float4*>(&x[s]);  // prefetch
                    const float d0 = v.x - P, d1 = v.y - P;
                    const float d2 = v.z - P, d3 = v.w - P;
                    a0 += fast_exp2(-(d0 * d0));
                    a1 += fast_exp2(-(d1 * d1));
                    a2 += fast_exp2(-(d2 * d2));
                    a3 += fast_exp2(-(d3 * d3));
                    v = nv;
                }
                const float d0 = v.x - P, d1 = v.y - P;
                const float d2 = v.z - P, d3 = v.w - P;
                a0 += fast_exp2(-(d0 * d0));
                a1 += fast_exp2(-(d1 * d1));
                a2 += fast_exp2(-(d2 * d2));
                a3 += fast_exp2(-(d3 * d3));
            }
            for (; s < shi; ++s) {
                const float d = x[s] - P;
                a0 += fast_exp2(-(d * d));
            }
            coar[e][ic] = ((a0 + a1) + (a2 + a3)) * inv_len;
        }
    }
    __syncthreads();   // samples in bufS now dead -> reuse as fine red

    // ---- Lagrange-cubic interpolation to the 512 fine points ----
    {
        const int g = t;                   // fine point; all 4 envs per thread
        const int ic = g >> 1;
        if ((g & 1) == 0) {
            #pragma unroll
            for (int q = 0; q < 4; ++q) bufS[q][g] = coar[q][ic];   // exact
        } else {
            const int b = min(max(ic - 1, 0), 252);
            float4 W;                      // nodes b..b+3, eval at ic+0.5
            if (ic == 0)        W = make_float4( 0.3125f,  0.9375f, -0.3125f,  0.0625f);
            else if (ic == 254) W = make_float4( 0.0625f, -0.3125f,  0.9375f,  0.3125f);
            else if (ic == 255) W = make_float4(-0.3125f,  1.3125f, -2.1875f,  2.1875f);
            else                W = make_float4(-0.0625f,  0.5625f,  0.5625f, -0.0625f);
            #pragma unroll
            for (int q = 0; q < 4; ++q)
                bufS[q][g] = W.x * coar[q][b]     + W.y * coar[q][b + 1]
                           + W.z * coar[q][b + 2] + W.w * coar[q][b + 3];
        }
    }
    __syncthreads();

    // ---- pairwise |diff| summed over g, all in-block ----
    {
        const float r0 = bufS[0][t], r1 = bufS[1][t], r2 = bufS[2][t], r3 = bufS[3][t];
        float pr[6];
        pr[0] = fabsf(r0 - r1);
        pr[1] = fabsf(r0 - r2);
        pr[2] = fabsf(r0 - r3);
        pr[3] = fabsf(r1 - r2);
        pr[4] = fabsf(r1 - r3);
        pr[5] = fabsf(r2 - r3);
        #pragma unroll
        for (int pi = 0; pi < 6; ++pi) {
            float v = pr[pi];
            #pragma unroll
            for (int off = 32; off >= 1; off >>= 1) v += __shfl_xor(v, off, 64);
            if ((t & 63) == 0) wred[t >> 6][pi] = v;
        }
    }
    __syncthreads();
    if (t == 0) {
        const float scale = csh[3];
        float v[6];
        #pragma unroll
        for (int pi = 0; pi < 6; ++pi) {
            float sm = 0.f;
            #pragma unroll
            for (int w = 0; w < 8; ++w) sm += wred[w][pi];
            v[pi] = sm * scale;
        }
        float testv = v[0];
        #pragma unroll
        for (int pi = 1; pi < 6; ++pi) testv = fmaxf(testv, v[pi]);
        const float trainv = fmaxf(fmaxf(v[0], v[1]), v[3]);  // pairs (0,1),(0,2),(1,2)
        out[lf] = trainv;
        out[256 + lf] = testv;
        __threadfence();   // make out[] visible device-wide before the atomic
        const int old = __hip_atomic_fetch_add(counter, 1, __ATOMIC_ACQ_REL,
                                               __HIP_MEMORY_SCOPE_AGENT);
        lastf = (old == 255);
    }
    __syncthreads();

    // ---- last finished block computes the two scalar outputs ----
    if (lastf && t < 64) {
        const int ff = t & 31;
        const int base = (t >= 32) ? 256 : 0;      // lanes 0-31: train, 32-63: test
        float m = -FLT_MAX;
        #pragma unroll
        for (int ll = 0; ll < 8; ++ll) {
            const float val = __hip_atomic_load(&out[base + ll * 32 + ff],
                                                __ATOMIC_RELAXED, __HIP_MEMORY_SCOPE_AGENT);
            m = fmaxf(m, val);
        }
        #pragma unroll
        for (int off = 16; off >= 1; off >>= 1) m += __shfl_xor(m, off, 32);
        if (ff == 0) out[512 + (base ? 1 : 0)] = m * (1.0f / 32.0f);
    }
}

extern "C" void kernel_launch(void* const* d_in, const int* in_sizes, int n_in,
                              void* d_out, int out_size, void* d_ws, size_t ws_size,
                              hipStream_t stream) {
    (void)in_sizes; (void)n_in; (void)out_size; (void)ws_size;
    const float* matrix = (const float*)d_in[0];
    const float* params = (const float*)d_in[1];
    const int*   dlen   = (const int*)d_in[2];
    float* out = (float*)d_out;
    float* ws  = (float*)d_ws;
    float* PT   = ws + PT_OFF;
    float* sxg  = ws + SX_OFF;
    float* sxxg = ws + SXX_OFF;
    float* minp = ws + MIN_OFF;
    float* maxp = ws + MAX_OFF;
    int*   cnt  = (int*)(ws + CNT_OFF);

    hipLaunchKernelGGL(stage_prep, dim3(256), dim3(256), 0, stream,
                       matrix, params, PT, sxg, sxxg, minp, maxp, cnt);
    hipLaunchKernelGGL(stage_kde2, dim3(256), dim3(512), 0, stream,
                       PT, sxg, sxxg, minp, maxp, dlen, cnt, out);
}

// Round 9
// 83.769 us; speedup vs baseline: 1.2212x; 1.0541x over previous
//
#include <hip/hip_runtime.h>
#include <float.h>

// E=4, L=8, S=512, F=32, G=512. KDE via linear-binned histogram + Gaussian
// convolution: exp() count per block drops from ~190K to ~68 (weight table).

#if __has_builtin(__builtin_amdgcn_exp2f)
__device__ __forceinline__ float fast_exp2(float x) { return __builtin_amdgcn_exp2f(x); }
#else
__device__ __forceinline__ float fast_exp2(float x) { return exp2f(x); }
#endif

#define MAXR 160     // max conv radius (bins); runtime R = ceil(3.5/h) ~ 67
#define PADL 160     // zero padding each side of the 513 hist bins
#define HW   840     // hist row width: PADL + 513 + PADR (slack-aligned)

// ---- workspace layout (float offsets) ----
#define PT_OFF    0        // proj^T [E][L][F][S] = 524288 floats (unscaled)
#define SX_OFF    524288   // [256 blk][32 f] sum(x)
#define SXX_OFF   532480   // [256 blk][32 f] sum(x^2)
#define MIN_OFF   540672   // [256] per-block min
#define MAX_OFF   540928   // [256] per-block max
#define CNT_OFF   541184   // completion counter (int)

// ---------- K1: proj^T + std partials + min/max (known-good, absmax 0.0) ----------
__global__ __launch_bounds__(256) void stage_prep(const float* __restrict__ matrix,
                                                  const float* __restrict__ params,
                                                  float* __restrict__ PT,
                                                  float* __restrict__ sxg,
                                                  float* __restrict__ sxxg,
                                                  float* __restrict__ minp,
                                                  float* __restrict__ maxp,
                                                  int* __restrict__ counter) {
    __shared__ float M[64][33];    // +1 pad: proj pass reads column-wise
    __shared__ float Pm[32][32];
    __shared__ float sxr[8][32], sxxr[8][32];
    __shared__ float rmin[4], rmax[4];
    const int bid = blockIdx.x;        // (e*8+l)*8 + stile
    const int s0 = (bid & 7) << 6;
    const int el = bid >> 3;
    const int t = threadIdx.x;
    if (bid == 0 && t == 0) *counter = 0;   // reset for K2's last-block trick
    {
        const float4 v = reinterpret_cast<const float4*>(params)[t];
        const int base = t << 2;
        Pm[base >> 5][base & 31]       = v.x;
        Pm[base >> 5][(base & 31) + 1] = v.y;
        Pm[base >> 5][(base & 31) + 2] = v.z;
        Pm[base >> 5][(base & 31) + 3] = v.w;
    }
    const float4* mb4 = reinterpret_cast<const float4*>(matrix + (size_t)(el * 512 + s0) * 32);
    #pragma unroll
    for (int k = t; k < 512; k += 256) {
        const float4 v = mb4[k];
        const int base = k << 2;
        M[base >> 5][base & 31]       = v.x;
        M[base >> 5][(base & 31) + 1] = v.y;
        M[base >> 5][(base & 31) + 2] = v.z;
        M[base >> 5][(base & 31) + 3] = v.w;
    }
    __syncthreads();
    {
        const int f = t & 31, r = t >> 5;
        float sx = 0.f, sxx = 0.f;
        #pragma unroll
        for (int k = 0; k < 8; ++k) {
            float v = M[r * 8 + k][f];
            sx += v; sxx += v * v;
        }
        sxr[r][f] = sx; sxxr[r][f] = sxx;
    }
    const int s = t & 63;
    const int g0 = t >> 6;
    float lmin = FLT_MAX, lmax = -FLT_MAX;
    #pragma unroll
    for (int pass = 0; pass < 8; ++pass) {
        const int g = (pass << 2) + g0;
        float acc = 0.f;
        #pragma unroll
        for (int fp = 0; fp < 32; ++fp) acc += M[s][fp] * Pm[fp][g];
        lmin = fminf(lmin, acc);
        lmax = fmaxf(lmax, acc);
        PT[(size_t)(el * 32 + g) * 512 + s0 + s] = acc;
    }
    #pragma unroll
    for (int off = 32; off >= 1; off >>= 1) {
        lmin = fminf(lmin, __shfl_xor(lmin, off, 64));
        lmax = fmaxf(lmax, __shfl_xor(lmax, off, 64));
    }
    if ((t & 63) == 0) { rmin[t >> 6] = lmin; rmax[t >> 6] = lmax; }
    __syncthreads();
    if (t < 32) {
        float a = 0.f, b = 0.f;
        #pragma unroll
        for (int r = 0; r < 8; ++r) { a += sxr[r][t]; b += sxxr[r][t]; }
        sxg[bid * 32 + t] = a;
        sxxg[bid * 32 + t] = b;
    }
    if (t == 0) {
        minp[bid] = fminf(fminf(rmin[0], rmin[1]), fminf(rmin[2], rmin[3]));
        maxp[bid] = fmaxf(fmaxf(rmax[0], rmax[1]), fmaxf(rmax[2], rmax[3]));
    }
}

// ---------- K2: consts + splat-histogram + Gaussian conv + pair L1 + outputs ----------
// 256 blocks = one per (l,f); 512 threads = (e = t>>7, 128 lanes per env).
__global__ __launch_bounds__(512) void stage_kde3(const float* __restrict__ PT,
                                                  const float* __restrict__ sxg,
                                                  const float* __restrict__ sxxg,
                                                  const float* __restrict__ minp,
                                                  const float* __restrict__ maxp,
                                                  const int* __restrict__ dlen,
                                                  int* __restrict__ counter,
                                                  float* __restrict__ out) {
    __shared__ int   histI[4][HW];     // fixed-point splat bins, later punned to float
    __shared__ float fine[4][512];     // red values on the fine grid
    __shared__ float wsh[MAXR + 4];    // Gaussian weight table
    __shared__ float wsum[8], wmn[8], wmx[8];
    __shared__ float wred[8][6];
    __shared__ float csh[8];
    __shared__ int   Rsh;
    __shared__ int   lensh[4];
    __shared__ int   lastf;
    const int t = threadIdx.x;
    const int lf = blockIdx.x;
    const int l = lf >> 5, f = lf & 31;

    if (t < 4) lensh[t] = dlen[(t << 3) + l];
    // zero histogram (pads included: int 0 == float 0.0 bitwise)
    {
        int* hflat = &histI[0][0];
        #pragma unroll
        for (int k = t; k < 4 * HW; k += 512) hflat[k] = 0;
    }

    // ---- consts: every block redundantly reduces K1's tiny partials ----
    {
        float sf = 0.f;
        #pragma unroll
        for (int tr = t; tr < 1024; tr += 512) {     // (e,l,f) triples
            const int el = tr >> 5, fc = tr & 31;
            const int base = el * 256 + fc;
            float Sx = 0.f, Sxx = 0.f;
            #pragma unroll
            for (int tile = 0; tile < 8; ++tile) { Sx += sxg[base + tile * 32]; Sxx += sxxg[base + tile * 32]; }
            const float mean = Sx * (1.0f / 512.0f);
            const float var = (Sxx - Sx * mean) * (1.0f / 511.0f);   // ddof=1
            sf += sqrtf(fmaxf(var, 0.f));
        }
        float mn = (t < 256) ? minp[t] : FLT_MAX;
        float mx = (t < 256) ? maxp[t] : -FLT_MAX;
        #pragma unroll
        for (int off = 32; off >= 1; off >>= 1) {
            sf += __shfl_xor(sf, off, 64);
            mn = fminf(mn, __shfl_xor(mn, off, 64));
            mx = fmaxf(mx, __shfl_xor(mx, off, 64));
        }
        if ((t & 63) == 0) { wsum[t >> 6] = sf; wmn[t >> 6] = mn; wmx[t >> 6] = mx; }
        __syncthreads();
        if (t == 0) {
            float s = 0.f, lo = FLT_MAX, hi = -FLT_MAX;
            #pragma unroll
            for (int w = 0; w < 8; ++w) {
                s += wsum[w]; lo = fminf(lo, wmn[w]); hi = fmaxf(hi, wmx[w]);
            }
            const float stdv = s * (1.0f / 1024.0f);
            const float left  = lo / stdv;
            const float right = hi / stdv;
            const float bw = 1.06f * 0.28717458874925877f;     // mean(std(m)) == 1
            const float delta = (right - left) * (1.0f / 512.0f);
            const float gstep = (right - left) * (1.0f / 511.0f);
            const float divisor = 2.5066282746310002f * bw;
            const float cpos = (0.5f / (bw * bw)) * 1.4426950408889634f;
            const float kf = sqrtf(cpos);          // kernel = exp2(-((x-p)*kf)^2)
            const float h = gstep * kf;            // grid step in scaled units
            csh[0] = left * kf;                    // leftk
            csh[1] = h;
            csh[2] = (1.0f / stdv) * kf;           // xscale
            csh[3] = delta * 0.5f / divisor;       // final scale
            csh[5] = 1.0f / h;                     // invh
            Rsh = min((int)(3.5f / h) + 1, MAXR);  // truncation: erfc-tail ~1e-5
        }
    }
    __syncthreads();
    const float h = csh[1];
    const int R = Rsh;

    // ---- weight table: the ONLY exps in the kernel (~R+1 of them) ----
    if (t <= R) {
        const float u = (float)t * h;
        wsh[t] = fast_exp2(-(u * u));
    }

    // ---- linear splat into fixed-point bins ----
    const int e = t >> 7;
    {
        const int sbase = (t & 127) << 2;
        const int lenE = lensh[e];
        const size_t row = ((size_t)(((e << 3) + l) * 32 + f) << 9);
        const float4 xv = *reinterpret_cast<const float4*>(&PT[row + sbase]);
        const float A = csh[2] * csh[5];           // u = raw*A - B  in bin units
        const float B = csh[0] * csh[5];
        float uu[4] = { fmaf(xv.x, A, -B), fmaf(xv.y, A, -B),
                        fmaf(xv.z, A, -B), fmaf(xv.w, A, -B) };
        #pragma unroll
        for (int q = 0; q < 4; ++q) {
            if (sbase + q < lenE) {
                const float u = fminf(fmaxf(uu[q], 0.f), 511.f);
                const int   b = (int)u;
                const float fr = u - (float)b;
                const int w1 = (int)(fr * 16384.f + 0.5f);
                atomicAdd(&histI[e][PADL + b], 16384 - w1);
                atomicAdd(&histI[e][PADL + b + 1], w1);
            }
        }
    }
    __syncthreads();

    // ---- convert bins to float in place, folding 1/(16384*len) ----
    #pragma unroll
    for (int e2 = 0; e2 < 4; ++e2) {
        const float ce = (1.0f / 16384.0f) / (float)lensh[e2];
        for (int k = t; k < HW; k += 512) {
            const int iv = histI[e2][k];
            *reinterpret_cast<float*>(&histI[e2][k]) = (float)iv * ce;   // same thread RW
        }
    }
    __syncthreads();

    // ---- Gaussian convolution: thread = (e, g0), 4 fine points g0+128j ----
    {
        const float* __restrict__ hf = reinterpret_cast<const float*>(&histI[e][0]);
        const int g0 = t & 127;
        const int c0 = PADL + g0;
        const int c1 = c0 + 128;
        const int c2 = c0 + 256;
        const int c3 = c0 + 384;
        const float w0 = wsh[0];
        float a0 = w0 * hf[c0], a1 = w0 * hf[c1];
        float a2 = w0 * hf[c2], a3 = w0 * hf[c3];
        for (int d = 1; d <= R; ++d) {
            const float wd = wsh[d];
            a0 += wd * (hf[c0 + d] + hf[c0 - d]);
            a1 += wd * (hf[c1 + d] + hf[c1 - d]);
            a2 += wd * (hf[c2 + d] + hf[c2 - d]);
            a3 += wd * (hf[c3 + d] + hf[c3 - d]);
        }
        fine[e][g0]       = a0;
        fine[e][g0 + 128] = a1;
        fine[e][g0 + 256] = a2;
        fine[e][g0 + 384] = a3;
    }
    __syncthreads();

    // ---- pairwise |diff| summed over g, all in-block ----
    {
        const float r0 = fine[0][t], r1 = fine[1][t], r2 = fine[2][t], r3 = fine[3][t];
        float pr[6];
        pr[0] = fabsf(r0 - r1);
        pr[1] = fabsf(r0 - r2);
        pr[2] = fabsf(r0 - r3);
        pr[3] = fabsf(r1 - r2);
        pr[4] = fabsf(r1 - r3);
        pr[5] = fabsf(r2 - r3);
        #pragma unroll
        for (int pi = 0; pi < 6; ++pi) {
            float v = pr[pi];
            #pragma unroll
            for (int off = 32; off >= 1; off >>= 1) v += __shfl_xor(v, off, 64);
            if ((t & 63) == 0) wred[t >> 6][pi] = v;
        }
    }
    __syncthreads();
    if (t == 0) {
        const float scale = csh[3];
        float v[6];
        #pragma unroll
        for (int pi = 0; pi < 6; ++pi) {
            float sm = 0.f;
            #pragma unroll
            for (int w = 0; w < 8; ++w) sm += wred[w][pi];
            v[pi] = sm * scale;
        }
        float testv = v[0];
        #pragma unroll
        for (int pi = 1; pi < 6; ++pi) testv = fmaxf(testv, v[pi]);
        const float trainv = fmaxf(fmaxf(v[0], v[1]), v[3]);  // pairs (0,1),(0,2),(1,2)
        out[lf] = trainv;
        out[256 + lf] = testv;
        __threadfence();   // make out[] visible device-wide before the atomic
        const int old = __hip_atomic_fetch_add(counter, 1, __ATOMIC_ACQ_REL,
                                               __HIP_MEMORY_SCOPE_AGENT);
        lastf = (old == 255);
    }
    __syncthreads();

    // ---- last finished block computes the two scalar outputs ----
    if (lastf && t < 64) {
        const int ff = t & 31;
        const int base = (t >= 32) ? 256 : 0;      // lanes 0-31: train, 32-63: test
        float m = -FLT_MAX;
        #pragma unroll
        for (int ll = 0; ll < 8; ++ll) {
            const float val = __hip_atomic_load(&out[base + ll * 32 + ff],
                                                __ATOMIC_RELAXED, __HIP_MEMORY_SCOPE_AGENT);
            m = fmaxf(m, val);
        }
        #pragma unroll
        for (int off = 16; off >= 1; off >>= 1) m += __shfl_xor(m, off, 32);
        if (ff == 0) out[512 + (base ? 1 : 0)] = m * (1.0f / 32.0f);
    }
}

extern "C" void kernel_launch(void* const* d_in, const int* in_sizes, int n_in,
                              void* d_out, int out_size, void* d_ws, size_t ws_size,
                              hipStream_t stream) {
    (void)in_sizes; (void)n_in; (void)out_size; (void)ws_size;
    const float* matrix = (const float*)d_in[0];
    const float* params = (const float*)d_in[1];
    const int*   dlen   = (const int*)d_in[2];
    float* out = (float*)d_out;
    float* ws  = (float*)d_ws;
    float* PT   = ws + PT_OFF;
    float* sxg  = ws + SX_OFF;
    float* sxxg = ws + SXX_OFF;
    float* minp = ws + MIN_OFF;
    float* maxp = ws + MAX_OFF;
    int*   cnt  = (int*)(ws + CNT_OFF);

    hipLaunchKernelGGL(stage_prep, dim3(256), dim3(256), 0, stream,
                       matrix, params, PT, sxg, sxxg, minp, maxp, cnt);
    hipLaunchKernelGGL(stage_kde3, dim3(256), dim3(512), 0, stream,
                       PT, sxg, sxxg, minp, maxp, dlen, cnt, out);
}

// Round 10
// 82.417 us; speedup vs baseline: 1.2412x; 1.0164x over previous
//
#include <hip/hip_runtime.h>
#include <float.h>

// E=4, L=8, S=512, F=32, G=512. KDE via linear-binned histogram + Gaussian
// convolution (exp count ~2R/block). Conv vectorized: ds_read_b128 chunks.

#if __has_builtin(__builtin_amdgcn_exp2f)
__device__ __forceinline__ float fast_exp2(float x) { return __builtin_amdgcn_exp2f(x); }
#else
__device__ __forceinline__ float fast_exp2(float x) { return exp2f(x); }
#endif

#define MAXR 150     // max conv radius (bins); runtime R = ceil(3.5/h) ~ 67
#define PADL 160     // zero padding each side of the 513 hist bins
#define HW   840     // hist row width: PADL + 513 + PADR
#define WOFF 163     // center of symmetric weight table (163 % 4 == 3 -> aligned vec4)
#define WFULL 336    // weight table floats (84 float4)

// ---- workspace layout (float offsets) ----
#define PT_OFF    0        // proj^T [E][L][F][S] = 524288 floats (unscaled)
#define SX_OFF    524288   // [256 blk][32 f] sum(x)
#define SXX_OFF   532480   // [256 blk][32 f] sum(x^2)
#define MIN_OFF   540672   // [256] per-block min
#define MAX_OFF   540928   // [256] per-block max
#define CNT_OFF   541184   // completion counter (int)

// ---------- K1: proj^T + std partials + min/max (known-good, absmax 0.0) ----------
__global__ __launch_bounds__(256) void stage_prep(const float* __restrict__ matrix,
                                                  const float* __restrict__ params,
                                                  float* __restrict__ PT,
                                                  float* __restrict__ sxg,
                                                  float* __restrict__ sxxg,
                                                  float* __restrict__ minp,
                                                  float* __restrict__ maxp,
                                                  int* __restrict__ counter) {
    __shared__ float M[64][33];    // +1 pad: proj pass reads column-wise
    __shared__ float Pm[32][32];
    __shared__ float sxr[8][32], sxxr[8][32];
    __shared__ float rmin[4], rmax[4];
    const int bid = blockIdx.x;        // (e*8+l)*8 + stile
    const int s0 = (bid & 7) << 6;
    const int el = bid >> 3;
    const int t = threadIdx.x;
    if (bid == 0 && t == 0) *counter = 0;   // reset for K2's last-block trick
    {
        const float4 v = reinterpret_cast<const float4*>(params)[t];
        const int base = t << 2;
        Pm[base >> 5][base & 31]       = v.x;
        Pm[base >> 5][(base & 31) + 1] = v.y;
        Pm[base >> 5][(base & 31) + 2] = v.z;
        Pm[base >> 5][(base & 31) + 3] = v.w;
    }
    const float4* mb4 = reinterpret_cast<const float4*>(matrix + (size_t)(el * 512 + s0) * 32);
    #pragma unroll
    for (int k = t; k < 512; k += 256) {
        const float4 v = mb4[k];
        const int base = k << 2;
        M[base >> 5][base & 31]       = v.x;
        M[base >> 5][(base & 31) + 1] = v.y;
        M[base >> 5][(base & 31) + 2] = v.z;
        M[base >> 5][(base & 31) + 3] = v.w;
    }
    __syncthreads();
    {
        const int f = t & 31, r = t >> 5;
        float sx = 0.f, sxx = 0.f;
        #pragma unroll
        for (int k = 0; k < 8; ++k) {
            float v = M[r * 8 + k][f];
            sx += v; sxx += v * v;
        }
        sxr[r][f] = sx; sxxr[r][f] = sxx;
    }
    const int s = t & 63;
    const int g0 = t >> 6;
    float lmin = FLT_MAX, lmax = -FLT_MAX;
    #pragma unroll
    for (int pass = 0; pass < 8; ++pass) {
        const int g = (pass << 2) + g0;
        float acc = 0.f;
        #pragma unroll
        for (int fp = 0; fp < 32; ++fp) acc += M[s][fp] * Pm[fp][g];
        lmin = fminf(lmin, acc);
        lmax = fmaxf(lmax, acc);
        PT[(size_t)(el * 32 + g) * 512 + s0 + s] = acc;
    }
    #pragma unroll
    for (int off = 32; off >= 1; off >>= 1) {
        lmin = fminf(lmin, __shfl_xor(lmin, off, 64));
        lmax = fmaxf(lmax, __shfl_xor(lmax, off, 64));
    }
    if ((t & 63) == 0) { rmin[t >> 6] = lmin; rmax[t >> 6] = lmax; }
    __syncthreads();
    if (t < 32) {
        float a = 0.f, b = 0.f;
        #pragma unroll
        for (int r = 0; r < 8; ++r) { a += sxr[r][t]; b += sxxr[r][t]; }
        sxg[bid * 32 + t] = a;
        sxxg[bid * 32 + t] = b;
    }
    if (t == 0) {
        minp[bid] = fminf(fminf(rmin[0], rmin[1]), fminf(rmin[2], rmin[3]));
        maxp[bid] = fmaxf(fmaxf(rmax[0], rmax[1]), fmaxf(rmax[2], rmax[3]));
    }
}

// ---------- K2: consts + splat-histogram + vectorized Gaussian conv + outputs ----------
// 256 blocks = one per (l,f); 512 threads = (e = t>>7, idx = t&127).
__global__ __launch_bounds__(512) void stage_kde3(const float* __restrict__ PT,
                                                  const float* __restrict__ sxg,
                                                  const float* __restrict__ sxxg,
                                                  const float* __restrict__ minp,
                                                  const float* __restrict__ maxp,
                                                  const int* __restrict__ dlen,
                                                  int* __restrict__ counter,
                                                  float* __restrict__ out) {
    __shared__ __align__(16) int   histI[4][HW];  // fixed-point bins -> punned float
    __shared__ __align__(16) float fine[4][512];  // red values on the fine grid
    __shared__ __align__(16) float wfull[WFULL];  // symmetric weights, zero-padded
    __shared__ float wsum[8], wmn[8], wmx[8];
    __shared__ float wred[8][6];
    __shared__ float csh[8];
    __shared__ int   Rsh;
    __shared__ int   lensh[4];
    __shared__ int   lastf;
    const int t = threadIdx.x;
    const int lf = blockIdx.x;
    const int l = lf >> 5, f = lf & 31;

    if (t < 4) lensh[t] = dlen[(t << 3) + l];
    {   // zero histogram (pads included: int 0 == float 0.0 bitwise)
        int* hflat = &histI[0][0];
        #pragma unroll
        for (int k = t; k < 4 * HW; k += 512) hflat[k] = 0;
    }

    // ---- consts: every block redundantly reduces K1's tiny partials ----
    {
        float sf = 0.f;
        #pragma unroll
        for (int tr = t; tr < 1024; tr += 512) {     // (e,l,f) triples
            const int el = tr >> 5, fc = tr & 31;
            const int base = el * 256 + fc;
            float Sx = 0.f, Sxx = 0.f;
            #pragma unroll
            for (int tile = 0; tile < 8; ++tile) { Sx += sxg[base + tile * 32]; Sxx += sxxg[base + tile * 32]; }
            const float mean = Sx * (1.0f / 512.0f);
            const float var = (Sxx - Sx * mean) * (1.0f / 511.0f);   // ddof=1
            sf += sqrtf(fmaxf(var, 0.f));
        }
        float mn = (t < 256) ? minp[t] : FLT_MAX;
        float mx = (t < 256) ? maxp[t] : -FLT_MAX;
        #pragma unroll
        for (int off = 32; off >= 1; off >>= 1) {
            sf += __shfl_xor(sf, off, 64);
            mn = fminf(mn, __shfl_xor(mn, off, 64));
            mx = fmaxf(mx, __shfl_xor(mx, off, 64));
        }
        if ((t & 63) == 0) { wsum[t >> 6] = sf; wmn[t >> 6] = mn; wmx[t >> 6] = mx; }
        __syncthreads();
        if (t == 0) {
            float s = 0.f, lo = FLT_MAX, hi = -FLT_MAX;
            #pragma unroll
            for (int w = 0; w < 8; ++w) {
                s += wsum[w]; lo = fminf(lo, wmn[w]); hi = fmaxf(hi, wmx[w]);
            }
            const float stdv = s * (1.0f / 1024.0f);
            const float left  = lo / stdv;
            const float right = hi / stdv;
            const float bw = 1.06f * 0.28717458874925877f;     // mean(std(m)) == 1
            const float delta = (right - left) * (1.0f / 512.0f);
            const float gstep = (right - left) * (1.0f / 511.0f);
            const float divisor = 2.5066282746310002f * bw;
            const float cpos = (0.5f / (bw * bw)) * 1.4426950408889634f;
            const float kf = sqrtf(cpos);          // kernel = exp2(-((x-p)*kf)^2)
            const float h = gstep * kf;            // grid step in scaled units
            csh[0] = left * kf;                    // leftk
            csh[1] = h;
            csh[2] = (1.0f / stdv) * kf;           // xscale
            csh[3] = delta * 0.5f / divisor;       // final scale
            csh[5] = 1.0f / h;                     // invh
            Rsh = min((int)(3.5f / h) + 1, MAXR);  // truncation: tail ~1e-5
        }
    }
    __syncthreads();
    const float h = csh[1];
    const int R = Rsh;

    // ---- symmetric weight table (zero-padded), the ONLY exps in the kernel ----
    if (t < WFULL) {
        const int d = t - WOFF;
        const int ad = (d < 0) ? -d : d;
        const float u = (float)ad * h;
        wfull[t] = (ad <= R) ? fast_exp2(-(u * u)) : 0.f;
    }

    // ---- linear splat into fixed-point bins ----
    const int e = t >> 7;
    const int idx = t & 127;
    {
        const int sbase = idx << 2;
        const int lenE = lensh[e];
        const size_t row = ((size_t)(((e << 3) + l) * 32 + f) << 9);
        const float4 xv = *reinterpret_cast<const float4*>(&PT[row + sbase]);
        const float A = csh[2] * csh[5];           // u = raw*A - B  in bin units
        const float B = csh[0] * csh[5];
        float uu[4] = { fmaf(xv.x, A, -B), fmaf(xv.y, A, -B),
                        fmaf(xv.z, A, -B), fmaf(xv.w, A, -B) };
        #pragma unroll
        for (int q = 0; q < 4; ++q) {
            if (sbase + q < lenE) {
                const float u = fminf(fmaxf(uu[q], 0.f), 511.f);
                const int   b = (int)u;
                const float fr = u - (float)b;
                const int w1 = (int)(fr * 16384.f + 0.5f);
                atomicAdd(&histI[e][PADL + b], 16384 - w1);
                atomicAdd(&histI[e][PADL + b + 1], w1);
            }
        }
    }
    __syncthreads();

    // ---- convert bins to float in place, folding 1/(16384*len) ----
    #pragma unroll
    for (int e2 = 0; e2 < 4; ++e2) {
        const float ce = (1.0f / 16384.0f) / (float)lensh[e2];
        for (int k = t; k < HW; k += 512) {
            const int iv = histI[e2][k];
            *reinterpret_cast<float*>(&histI[e2][k]) = (float)iv * ce;   // same thread RW
        }
    }
    __syncthreads();

    // ---- vectorized conv: thread = (e, idx), 4 adjacent fine points 4*idx+j ----
    {
        const float4* __restrict__ hf4 =
            reinterpret_cast<const float4*>(&histI[e][0]);   // HW%4==0, aligned
        const float4* __restrict__ wf4 = reinterpret_cast<const float4*>(&wfull[0]);
        const int hbase = 40 + idx;            // (PADL + 4*idx) / 4
        const int i_lo = -((R + 3) >> 2) - 1;
        const int i_hi = (R + 3) >> 2;
        float o0 = 0.f, o1 = 0.f, o2 = 0.f, o3 = 0.f;
        float4 W0 = wf4[40 + i_lo];            // (WOFF-3+4*i)/4 = 40+i
        for (int i = i_lo; i <= i_hi; ++i) {
            const float4 W1 = wf4[41 + i];
            const float4 H = hf4[hbase + i];
            // weight(m,j) = wfull[WOFF + 4i + m - j]; q = m-j+3 -> W0[q<4], W1[q-4]
            o0 += H.x * W0.w + H.y * W1.x + H.z * W1.y + H.w * W1.z;
            o1 += H.x * W0.z + H.y * W0.w + H.z * W1.x + H.w * W1.y;
            o2 += H.x * W0.y + H.y * W0.z + H.z * W0.w + H.w * W1.x;
            o3 += H.x * W0.x + H.y * W0.y + H.z * W0.z + H.w * W0.w;
            W0 = W1;
        }
        *reinterpret_cast<float4*>(&fine[e][idx << 2]) = make_float4(o0, o1, o2, o3);
    }
    __syncthreads();

    // ---- pairwise |diff| summed over g, all in-block ----
    {
        const float r0 = fine[0][t], r1 = fine[1][t], r2 = fine[2][t], r3 = fine[3][t];
        float pr[6];
        pr[0] = fabsf(r0 - r1);
        pr[1] = fabsf(r0 - r2);
        pr[2] = fabsf(r0 - r3);
        pr[3] = fabsf(r1 - r2);
        pr[4] = fabsf(r1 - r3);
        pr[5] = fabsf(r2 - r3);
        #pragma unroll
        for (int pi = 0; pi < 6; ++pi) {
            float v = pr[pi];
            #pragma unroll
            for (int off = 32; off >= 1; off >>= 1) v += __shfl_xor(v, off, 64);
            if ((t & 63) == 0) wred[t >> 6][pi] = v;
        }
    }
    __syncthreads();
    if (t == 0) {
        const float scale = csh[3];
        float v[6];
        #pragma unroll
        for (int pi = 0; pi < 6; ++pi) {
            float sm = 0.f;
            #pragma unroll
            for (int w = 0; w < 8; ++w) sm += wred[w][pi];
            v[pi] = sm * scale;
        }
        float testv = v[0];
        #pragma unroll
        for (int pi = 1; pi < 6; ++pi) testv = fmaxf(testv, v[pi]);
        const float trainv = fmaxf(fmaxf(v[0], v[1]), v[3]);  // pairs (0,1),(0,2),(1,2)
        out[lf] = trainv;
        out[256 + lf] = testv;
        __threadfence();   // make out[] visible device-wide before the atomic
        const int old = __hip_atomic_fetch_add(counter, 1, __ATOMIC_ACQ_REL,
                                               __HIP_MEMORY_SCOPE_AGENT);
        lastf = (old == 255);
    }
    __syncthreads();

    // ---- last finished block computes the two scalar outputs ----
    if (lastf && t < 64) {
        const int ff = t & 31;
        const int base = (t >= 32) ? 256 : 0;      // lanes 0-31: train, 32-63: test
        float m = -FLT_MAX;
        #pragma unroll
        for (int ll = 0; ll < 8; ++ll) {
            const float val = __hip_atomic_load(&out[base + ll * 32 + ff],
                                                __ATOMIC_RELAXED, __HIP_MEMORY_SCOPE_AGENT);
            m = fmaxf(m, val);
        }
        #pragma unroll
        for (int off = 16; off >= 1; off >>= 1) m += __shfl_xor(m, off, 32);
        if (ff == 0) out[512 + (base ? 1 : 0)] = m * (1.0f / 32.0f);
    }
}

extern "C" void kernel_launch(void* const* d_in, const int* in_sizes, int n_in,
                              void* d_out, int out_size, void* d_ws, size_t ws_size,
                              hipStream_t stream) {
    (void)in_sizes; (void)n_in; (void)out_size; (void)ws_size;
    const float* matrix = (const float*)d_in[0];
    const float* params = (const float*)d_in[1];
    const int*   dlen   = (const int*)d_in[2];
    float* out = (float*)d_out;
    float* ws  = (float*)d_ws;
    float* PT   = ws + PT_OFF;
    float* sxg  = ws + SX_OFF;
    float* sxxg = ws + SXX_OFF;
    float* minp = ws + MIN_OFF;
    float* maxp = ws + MAX_OFF;
    int*   cnt  = (int*)(ws + CNT_OFF);

    hipLaunchKernelGGL(stage_prep, dim3(256), dim3(256), 0, stream,
                       matrix, params, PT, sxg, sxxg, minp, maxp, cnt);
    hipLaunchKernelGGL(stage_kde3, dim3(256), dim3(512), 0, stream,
                       PT, sxg, sxxg, minp, maxp, dlen, cnt, out);
}